// Round 6
// baseline (178.913 us; speedup 1.0000x reference)
//
#include <hip/hip_runtime.h>
#include <math.h>
#include <stdint.h>

// Sizes (fixed): B=2, S=L=1024, h=16, k=128, d_c=512, d_cq=1536, r=64, dim_q=2048

typedef __attribute__((ext_vector_type(8))) short short8;
typedef __attribute__((ext_vector_type(4))) float f32x4;

#define GLOAD16(gsrc, ldst)                                                            \
  __builtin_amdgcn_global_load_lds((const __attribute__((address_space(1))) void*)(gsrc), \
                                   (__attribute__((address_space(3))) void*)(ldst), 16, 0, 0)

__device__ inline uint16_t f2b(float x) {  // round-to-nearest-even f32 -> bf16
  uint32_t u = __builtin_bit_cast(uint32_t, x);
  u += 0x7fff + ((u >> 16) & 1);
  return (uint16_t)(u >> 16);
}
__device__ inline float b2f(uint16_t b) {
  uint32_t u = ((uint32_t)b) << 16;
  return __builtin_bit_cast(float, u);
}
__device__ inline uint32_t cvtpk_bf16(float lo, float hi) {  // packs 2 f32 -> 2 bf16 (RNE)
  uint32_t d;
  asm("v_cvt_pk_bf16_f32 %0, %1, %2" : "=v"(d) : "v"(lo), "v"(hi));
  return d;
}

// ---------------- fused f32 -> bf16 convert for 5 buffers (8 el/thread) ----------------
// block counts: hq 2048 | kv 512 | wkv 512 | Wo 2048 | wkcq 1536  (total 6656)
__global__ __launch_bounds__(256) void convert5_kernel(
    const float* __restrict__ s0, uint16_t* __restrict__ t0, const float* __restrict__ s1,
    uint16_t* __restrict__ t1, const float* __restrict__ s2, uint16_t* __restrict__ t2,
    const float* __restrict__ s3, uint16_t* __restrict__ t3, const float* __restrict__ s4,
    uint16_t* __restrict__ t4) {
  int bid = blockIdx.x;
  const float* s;
  uint16_t* t;
  int off;
  if (bid < 2048) { s = s0; t = t0; off = bid; }
  else if (bid < 2560) { s = s1; t = t1; off = bid - 2048; }
  else if (bid < 3072) { s = s2; t = t2; off = bid - 2560; }
  else if (bid < 5120) { s = s3; t = t3; off = bid - 3072; }
  else { s = s4; t = t4; off = bid - 5120; }
  int i = off * 256 + threadIdx.x;
  const float4* s4v = (const float4*)s;
  float4 a = s4v[i * 2], b = s4v[i * 2 + 1];
  union {
    uint16_t u[8];
    uint4 v;
  } o;
  o.u[0] = f2b(a.x); o.u[1] = f2b(a.y); o.u[2] = f2b(a.z); o.u[3] = f2b(a.w);
  o.u[4] = f2b(b.x); o.u[5] = f2b(b.y); o.u[6] = f2b(b.z); o.u[7] = f2b(b.w);
  ((uint4*)t)[i] = o.v;
}

// ---------------- tiled transpose + convert: src f32 [R][C] -> dst bf16 [C][R] ----------------
__global__ __launch_bounds__(256) void transpose_conv_kernel(const float* __restrict__ src,
                                                             uint16_t* __restrict__ dst,
                                                             int R, int C, int sOff, int dOff) {
  __shared__ float t[32][33];
  src += (size_t)blockIdx.z * sOff;
  dst += (size_t)blockIdx.z * dOff;
  int r0 = blockIdx.x * 32, c0 = blockIdx.y * 32;
  int tr = threadIdx.x >> 5, tc = threadIdx.x & 31;
#pragma unroll
  for (int i = 0; i < 4; ++i) t[tr + i * 8][tc] = src[(size_t)(r0 + tr + i * 8) * C + c0 + tc];
  __syncthreads();
#pragma unroll
  for (int i = 0; i < 4; ++i)
    dst[(size_t)(c0 + tr + i * 8) * R + r0 + tc] = f2b(t[tc][tr + i * 8]);
}

// ---------------- rope tables: K-tables plain, Q-tables pre-scaled by log2(e) ----------------
__global__ __launch_bounds__(64) void rope_tables_kernel(float* __restrict__ cosK,
                                                         float* __restrict__ sinK,
                                                         float* __restrict__ cosQ,
                                                         float* __restrict__ sinQ) {
  const float LOG2E = 1.44269504088896341f;
  int s = blockIdx.x;
  int j = threadIdx.x;
  int i = j & 31;
  float inv = powf(10000.0f, -(float)(2 * i) / 64.0f);
  float ang = (float)s * inv;
  float c = cosf(ang), sn = sinf(ang);
  cosK[s * 64 + j] = c;
  sinK[s * 64 + j] = sn;
  cosQ[s * 64 + j] = c * LOG2E;
  sinQ[s * 64 + j] = sn * LOG2E;
}

// ---------------- MFMA GEMM: C[.., M, N] = A[z][M,K]bf16 @ Bt[z][N,K]bf16^T ----------------
// Tile BM x 128, BK=64, 256 thr (4 waves 2x2), XOR slot swizzle, global_load_lds staging.
// EPI 0: f32 row-major; 1: bf16 row-major; 2: bf16 VhT layout; 3: bf16 + fused rope.
// SPLITK>1: z = zh*SPLITK+zk; A/Bt K-offset zk*K; C indexed linearly by z (cZ).
template <int BM, int EPI, int SPLITK = 1>
__global__ __launch_bounds__(256) void gemm_mfma_kernel(const uint16_t* __restrict__ A,
                                                        const uint16_t* __restrict__ Bt,
                                                        void* __restrict__ Cv, int K, int lda,
                                                        int ldb, int ldc, int aZ, int bZ, int cZ,
                                                        const float* __restrict__ rc,
                                                        const float* __restrict__ rs) {
  constexpr int MT = BM / 32;  // m-fragments per wave (2 or 4)
  __shared__ __align__(16) uint16_t As[BM * 64];
  __shared__ __align__(16) uint16_t Bs[128 * 64];
  int z = blockIdx.z;
  if (SPLITK > 1) {
    int zh = z / SPLITK, zk = z % SPLITK;
    A += (size_t)zh * aZ + (size_t)zk * K;
    Bt += (size_t)zh * bZ + (size_t)zk * K;
  } else {
    A += (size_t)z * aZ;
    Bt += (size_t)z * bZ;
  }
  int m0 = blockIdx.x * BM, n0 = blockIdx.y * 128;
  int tid = threadIdx.x;
  int wave = tid >> 6, lane = tid & 63;
  int wm = wave >> 1, wn = wave & 1;
  int rS = lane >> 3, sl = lane & 7;
  int lr = lane >> 4, lc = lane & 15;
  f32x4 acc[MT][4] = {};
  for (int k0 = 0; k0 < K; k0 += 64) {
    __syncthreads();
#pragma unroll
    for (int i = 0; i < MT; ++i) {
      int idx = wave * MT + i;
      int row = idx * 8 + rS;
      GLOAD16(A + (size_t)(m0 + row) * lda + k0 + ((sl ^ (row & 7)) << 3),
              (uint8_t*)As + idx * 1024);
    }
#pragma unroll
    for (int i = 0; i < 4; ++i) {
      int idx = wave * 4 + i;
      int row = idx * 8 + rS;
      GLOAD16(Bt + (size_t)(n0 + row) * ldb + k0 + ((sl ^ (row & 7)) << 3),
              (uint8_t*)Bs + idx * 1024);
    }
    __syncthreads();
    short8 af[MT][2], bf[4][2];
#pragma unroll
    for (int t = 0; t < MT; ++t)
#pragma unroll
      for (int ks = 0; ks < 2; ++ks) {
        int slot = ks * 4 + lr;
        int ra = wm * (BM / 2) + t * 16 + lc;
        af[t][ks] = *(const short8*)((const uint8_t*)As + ra * 128 + ((slot ^ (ra & 7)) << 4));
      }
#pragma unroll
    for (int t = 0; t < 4; ++t)
#pragma unroll
      for (int ks = 0; ks < 2; ++ks) {
        int slot = ks * 4 + lr;
        int rb = wn * 64 + t * 16 + lc;
        bf[t][ks] = *(const short8*)((const uint8_t*)Bs + rb * 128 + ((slot ^ (rb & 7)) << 4));
      }
    __builtin_amdgcn_s_setprio(1);
#pragma unroll
    for (int mt = 0; mt < MT; ++mt)
#pragma unroll
      for (int nt = 0; nt < 4; ++nt) {
        acc[mt][nt] =
            __builtin_amdgcn_mfma_f32_16x16x32_bf16(af[mt][0], bf[nt][0], acc[mt][nt], 0, 0, 0);
        acc[mt][nt] =
            __builtin_amdgcn_mfma_f32_16x16x32_bf16(af[mt][1], bf[nt][1], acc[mt][nt], 0, 0, 0);
      }
    __builtin_amdgcn_s_setprio(0);
  }
  if (EPI == 3) {
#pragma unroll
    for (int mt = 0; mt < MT; ++mt)
#pragma unroll
      for (int nt = 0; nt < 4; ++nt)
#pragma unroll
        for (int r = 0; r < 4; ++r) {
          int m = m0 + wm * (BM / 2) + mt * 16 + lr * 4 + r;
          int n = n0 + wn * 64 + nt * 16 + lc;
          int pos = m & 1023, j = n & 63;
          float x = acc[mt][nt][r];
          float prt = acc[mt][nt ^ 2][r];
          float rot = (nt & 2) ? prt : -prt;
          float v = fmaf(x, rc[pos * 64 + j], rot * rs[pos * 64 + j]);
          ((uint16_t*)Cv)[(size_t)m * ldc + n] = f2b(v);
        }
  } else {
#pragma unroll
    for (int mt = 0; mt < MT; ++mt)
#pragma unroll
      for (int nt = 0; nt < 4; ++nt)
#pragma unroll
        for (int r = 0; r < 4; ++r) {
          int m = m0 + wm * (BM / 2) + mt * 16 + lr * 4 + r;
          int n = n0 + wn * 64 + nt * 16 + lc;
          float v = acc[mt][nt][r];
          if (EPI == 0)
            ((float*)Cv)[(size_t)z * cZ + (size_t)m * ldc + n] = v;
          else if (EPI == 1)
            ((uint16_t*)Cv)[(size_t)z * cZ + (size_t)m * ldc + n] = f2b(v);
          else
            ((uint16_t*)Cv)[((size_t)((m >> 10) * 2048 + n)) * 1024 + (m & 1023)] = f2b(v);
        }
  }
}

// ---------------- reduce fold1 split-K partials f32 -> bf16 ----------------
// tp: [16 heads][4 splits][8192], out: [16][8192] bf16
__global__ __launch_bounds__(256) void reduce1_kernel(const float* __restrict__ tp,
                                                      uint16_t* __restrict__ tmpT) {
  int gid = blockIdx.x * 256 + threadIdx.x;  // 131072
  int zh = gid >> 13, e = gid & 8191;
  const float* b = tp + (size_t)zh * 32768 + e;
  tmpT[gid] = f2b(b[0] + b[8192] + b[16384] + b[24576]);
}

// ---------------- MFMA flash attention, split over L (grid.z=4) ----------------
// grid (bh=32, stile=16, lsplit=4), 256 thr = 4 waves; wave owns 16 q-rows.
// Writes normalized bf16 partial o_part[z][(b*16+h)*1024+s][128] + ml[z][row] = {m,l}
__global__ __launch_bounds__(256) void flash3_kernel(const uint16_t* __restrict__ qrb,
                                                     const uint16_t* __restrict__ krb,
                                                     const uint16_t* __restrict__ VhT,
                                                     uint16_t* __restrict__ o_part,
                                                     float2* __restrict__ ml) {
  __shared__ __align__(16) uint16_t Ks[64 * 64];     // rows l, 64 r (128B, swizzled)
  __shared__ __align__(16) uint16_t Vs[128 * 64];    // rows kk, 64 l (128B, swizzled)
  __shared__ __align__(16) uint16_t Ps[4][16 * 64];  // per-wave P, swizzled
  int bh = blockIdx.x;
  int b = bh >> 4, h = bh & 15;
  int s0 = blockIdx.y * 64;
  int zsp = blockIdx.z;
  int tid = threadIdx.x, wave = tid >> 6, lane = tid & 63;
  int lr = lane >> 4, lc = lane & 15;
  int rS = lane >> 3, sl = lane & 7;

  const uint16_t* qrow = qrb + (size_t)(b * 1024 + s0 + wave * 16 + lc) * 1024 + h * 64;
  short8 qa[2];
  qa[0] = *(const short8*)(qrow + lr * 8);
  qa[1] = *(const short8*)(qrow + 32 + lr * 8);

  float m_run[4], l_run[4];
#pragma unroll
  for (int r = 0; r < 4; ++r) {
    m_run[r] = -1e30f;
    l_run[r] = 0.f;
  }
  f32x4 o[8] = {};

  const uint16_t* krbase = krb + (size_t)(b * 1024) * 1024 + h * 64;
  const uint16_t* vtbase = VhT + (size_t)(b * 2048 + h * 128) * 1024;

  for (int l0 = zsp * 256; l0 < zsp * 256 + 256; l0 += 64) {
    __syncthreads();
#pragma unroll
    for (int i = 0; i < 2; ++i) {  // stage K tile: 8KB
      int idx = wave * 2 + i;
      int row = idx * 8 + rS;
      GLOAD16(krbase + (size_t)(l0 + row) * 1024 + ((sl ^ (row & 7)) << 3),
              (uint8_t*)Ks + idx * 1024);
    }
#pragma unroll
    for (int i = 0; i < 4; ++i) {  // stage V^T tile: 16KB
      int idx = wave * 4 + i;
      int row = idx * 8 + rS;
      GLOAD16(vtbase + (size_t)row * 1024 + l0 + ((sl ^ (row & 7)) << 3),
              (uint8_t*)Vs + idx * 1024);
    }
    __syncthreads();

    // QK^T: sc[nt] covers cols nt*16+lc, rows lr*4+r   (log2 domain; q pre-scaled)
    f32x4 sc[4];
    __builtin_amdgcn_s_setprio(1);
#pragma unroll
    for (int nt = 0; nt < 4; ++nt) {
      int rowk = nt * 16 + lc;
      short8 kb0 = *(const short8*)((const uint8_t*)Ks + rowk * 128 + ((lr ^ (rowk & 7)) << 4));
      short8 kb1 =
          *(const short8*)((const uint8_t*)Ks + rowk * 128 + (((4 + lr) ^ (rowk & 7)) << 4));
      f32x4 z = {};
      z = __builtin_amdgcn_mfma_f32_16x16x32_bf16(qa[0], kb0, z, 0, 0, 0);
      sc[nt] = __builtin_amdgcn_mfma_f32_16x16x32_bf16(qa[1], kb1, z, 0, 0, 0);
    }
    __builtin_amdgcn_s_setprio(0);

    // per-row tile max (16-lane reduce)
    float mx[4];
#pragma unroll
    for (int r = 0; r < 4; ++r) {
      float m = fmaxf(fmaxf(sc[0][r], sc[1][r]), fmaxf(sc[2][r], sc[3][r]));
      m = fmaxf(m, __shfl_xor(m, 1));
      m = fmaxf(m, __shfl_xor(m, 2));
      m = fmaxf(m, __shfl_xor(m, 4));
      mx[r] = fmaxf(m, __shfl_xor(m, 8));
    }
    // defer-max: skip rescale when all rows grew <= 8 (log2 domain -> P <= 256)
    bool grow = false;
#pragma unroll
    for (int r = 0; r < 4; ++r) grow |= (mx[r] > m_run[r] + 8.0f);
    bool upd = (__ballot(grow) != 0ULL);  // wave-uniform
    float scale[4];
    if (upd) {
#pragma unroll
      for (int r = 0; r < 4; ++r) {
        float mn = fmaxf(m_run[r], mx[r]);
        scale[r] = exp2f(m_run[r] - mn);
        m_run[r] = mn;
      }
    }
    float ps[4] = {0.f, 0.f, 0.f, 0.f};
#pragma unroll
    for (int nt = 0; nt < 4; ++nt) {
      int pcol = nt * 16 + lc;
#pragma unroll
      for (int rp = 0; rp < 2; ++rp) {
        float p0 = exp2f(sc[nt][rp * 2] - m_run[rp * 2]);
        float p1 = exp2f(sc[nt][rp * 2 + 1] - m_run[rp * 2 + 1]);
        ps[rp * 2] += p0;
        ps[rp * 2 + 1] += p1;
        uint32_t u = cvtpk_bf16(p0, p1);
        int prow0 = lr * 4 + rp * 2;
        uint32_t a0 = prow0 * 128 + ((((pcol >> 3) ^ (prow0 & 7))) << 4) + (pcol & 7) * 2;
        int prow1 = prow0 + 1;
        uint32_t a1 = prow1 * 128 + ((((pcol >> 3) ^ (prow1 & 7))) << 4) + (pcol & 7) * 2;
        *(uint16_t*)((uint8_t*)Ps[wave] + a0) = (uint16_t)u;
        *(uint16_t*)((uint8_t*)Ps[wave] + a1) = (uint16_t)(u >> 16);
      }
    }
#pragma unroll
    for (int r = 0; r < 4; ++r) {
      float s = ps[r];
      s += __shfl_xor(s, 1);
      s += __shfl_xor(s, 2);
      s += __shfl_xor(s, 4);
      s += __shfl_xor(s, 8);
      ps[r] = s;
    }
    if (upd) {
#pragma unroll
      for (int r = 0; r < 4; ++r) l_run[r] = l_run[r] * scale[r] + ps[r];
#pragma unroll
      for (int nt = 0; nt < 8; ++nt)
#pragma unroll
        for (int r = 0; r < 4; ++r) o[nt][r] *= scale[r];
    } else {
#pragma unroll
      for (int r = 0; r < 4; ++r) l_run[r] += ps[r];
    }

    // P as A-fragment (wave-local LDS bounce; compiler inserts lgkmcnt)
    short8 pa[2];
#pragma unroll
    for (int ks = 0; ks < 2; ++ks) {
      int slot = ks * 4 + lr;
      pa[ks] = *(const short8*)((const uint8_t*)Ps[wave] + lc * 128 + ((slot ^ (lc & 7)) << 4));
    }
    // PV: o[nt] covers kk cols nt*16+lc
    __builtin_amdgcn_s_setprio(1);
#pragma unroll
    for (int nt = 0; nt < 8; ++nt) {
      int rowv = nt * 16 + lc;
      short8 vb0 = *(const short8*)((const uint8_t*)Vs + rowv * 128 + ((lr ^ (rowv & 7)) << 4));
      short8 vb1 =
          *(const short8*)((const uint8_t*)Vs + rowv * 128 + (((4 + lr) ^ (rowv & 7)) << 4));
      o[nt] = __builtin_amdgcn_mfma_f32_16x16x32_bf16(pa[0], vb0, o[nt], 0, 0, 0);
      o[nt] = __builtin_amdgcn_mfma_f32_16x16x32_bf16(pa[1], vb1, o[nt], 0, 0, 0);
    }
    __builtin_amdgcn_s_setprio(0);
  }
  // epilogue: normalized bf16 partial + (m,l) per row
  int rowbase = (b * 16 + h) * 1024 + s0 + wave * 16;
  uint16_t* opr = o_part + ((size_t)zsp * 32768 + rowbase) * 128;
#pragma unroll
  for (int nt = 0; nt < 8; ++nt)
#pragma unroll
    for (int r = 0; r < 4; ++r)
      opr[(size_t)(lr * 4 + r) * 128 + nt * 16 + lc] = f2b(o[nt][r] / l_run[r]);
  if (lc == 0) {
    float2* mlp = ml + (size_t)zsp * 32768 + rowbase;
#pragma unroll
    for (int r = 0; r < 4; ++r) mlp[lr * 4 + r] = make_float2(m_run[r], l_run[r]);
  }
}

// ---------------- combine split-L partials -> ctxlatb bf16 [b*1024+s][2048] ----------------
// grid 2048, block 256: 16 rows/block, 16 threads/row, 8 cols/thread
__global__ __launch_bounds__(256) void combine_kernel(const uint16_t* __restrict__ op,
                                                      const float2* __restrict__ ml,
                                                      uint16_t* __restrict__ ctxlatb) {
  int row = blockIdx.x * 16 + (threadIdx.x >> 4);
  int kk0 = (threadIdx.x & 15) * 8;
  float2 m0 = ml[row], m1 = ml[32768 + row], m2 = ml[65536 + row], m3 = ml[98304 + row];
  float M = fmaxf(fmaxf(m0.x, m1.x), fmaxf(m2.x, m3.x));
  float w0 = m0.y * exp2f(m0.x - M);
  float w1 = m1.y * exp2f(m1.x - M);
  float w2 = m2.y * exp2f(m2.x - M);
  float w3 = m3.y * exp2f(m3.x - M);
  float inv = 1.0f / (w0 + w1 + w2 + w3);
  w0 *= inv; w1 *= inv; w2 *= inv; w3 *= inv;
  short8 v0 = *(const short8*)(op + (size_t)row * 128 + kk0);
  short8 v1 = *(const short8*)(op + 4194304ull + (size_t)row * 128 + kk0);
  short8 v2 = *(const short8*)(op + 8388608ull + (size_t)row * 128 + kk0);
  short8 v3 = *(const short8*)(op + 12582912ull + (size_t)row * 128 + kk0);
  int b = row >> 14, h = (row >> 10) & 15, s = row & 1023;
  uint16_t* outp = ctxlatb + ((size_t)(b * 1024 + s)) * 2048 + h * 128 + kk0;
  uint16_t res[8];
#pragma unroll
  for (int j = 0; j < 8; ++j) {
    float a = b2f((uint16_t)v0[j]) * w0 + b2f((uint16_t)v1[j]) * w1 +
              b2f((uint16_t)v2[j]) * w2 + b2f((uint16_t)v3[j]) * w3;
    res[j] = f2b(a);
  }
  *(uint4*)outp = *(uint4*)res;
}

extern "C" void kernel_launch(void* const* d_in, const int* in_sizes, int n_in,
                              void* d_out, int out_size, void* d_ws, size_t ws_size,
                              hipStream_t stream) {
  const float* hidden_q = (const float*)d_in[0];
  const float* kv_c = (const float*)d_in[1];
  const float* Wq = (const float*)d_in[2];
  const float* w_kc_q = (const float*)d_in[3];
  const float* W_qr = (const float*)d_in[4];
  const float* W_kr = (const float*)d_in[5];
  const float* w_kc_kv = (const float*)d_in[6];
  const float* Wo = (const float*)d_in[7];
  float* out = (float*)d_out;

  const size_t MB = 1024 * 1024;
  uint8_t* base = (uint8_t*)d_ws;
  // --- live through flash/combine ---
  uint16_t* Wob = (uint16_t*)(base + 0 * MB);       // 8 MiB
  uint16_t* qrb = (uint16_t*)(base + 8 * MB);       // 4 MiB [2048][1024] (q pre-scaled log2e)
  uint16_t* krb = (uint16_t*)(base + 12 * MB);      // 4 MiB [2048][1024]
  uint16_t* VhT = (uint16_t*)(base + 16 * MB);      // 8 MiB [b*2048+h*128+kk][1024]
  uint16_t* ctxlatb = (uint16_t*)(base + 24 * MB);  // 8 MiB [b*1024+s][2048]
  // --- dead by flash time (prep stage) ---
  float* cosK = (float*)(base + 32 * MB);           // 256 KiB each
  float* sinK = (float*)(base + 32 * MB + 262144);
  float* cosQ = (float*)(base + 32 * MB + 524288);
  float* sinQ = (float*)(base + 32 * MB + 786432);
  uint16_t* hqb = (uint16_t*)(base + 33 * MB);      // 8 MiB
  uint16_t* kvb = (uint16_t*)(base + 41 * MB);      // 2 MiB
  uint16_t* wkvb = (uint16_t*)(base + 43 * MB);     // 2 MiB
  uint16_t* WqT = (uint16_t*)(base + 45 * MB);      // 8 MiB
  uint16_t* WqrT = (uint16_t*)(base + 53 * MB);     // 3 MiB
  uint16_t* wkcqb = (uint16_t*)(base + 56 * MB);    // 6 MiB
  float* tmp1 = (float*)(base + 62 * MB);           // 2 MiB f32 fold1 partials [16][4][8192]
  uint16_t* tmpT = (uint16_t*)(base + 64 * MB);     // 256 KiB
  uint16_t* WkrT = (uint16_t*)(base + 64 * MB + 262144);  // 1 MiB (ends 65.25 MiB)
  // --- flash-time overlays of the dead prep region ---
  uint16_t* o_part = (uint16_t*)(base + 32 * MB);   // 32 MiB bf16 [4][32768][128]
  float2* mlbuf = (float2*)(base + 64 * MB);        // 1 MiB f32x2 [4][32768]

  convert5_kernel<<<dim3(6656), dim3(256), 0, stream>>>(hidden_q, hqb, kv_c, kvb, w_kc_kv, wkvb,
                                                        Wo, Wob, w_kc_q, wkcqb);
  rope_tables_kernel<<<dim3(1024), dim3(64), 0, stream>>>(cosK, sinK, cosQ, sinQ);
  // W_qr [h][1536][64] -> WqrT [h][64][1536]
  transpose_conv_kernel<<<dim3(48, 2, 16), dim3(256), 0, stream>>>((const float*)W_qr, WqrT, 1536,
                                                                   64, 98304, 98304);
  // Wq [2048][2048] -> WqT [2048][2048]
  transpose_conv_kernel<<<dim3(64, 64, 1), dim3(256), 0, stream>>>(Wq, WqT, 2048, 2048, 0, 0);
  // W_kr [h][512][64] -> WkrT [h][64][512]
  transpose_conv_kernel<<<dim3(16, 2, 16), dim3(256), 0, stream>>>((const float*)W_kr, WkrT, 512,
                                                                   64, 32768, 32768);
  // fold1 split-K x4: tmp1[h*4+zk] = partial sum over q in [zk*384,(zk+1)*384)
  gemm_mfma_kernel<64, 0, 4><<<dim3(1, 1, 64), dim3(256), 0, stream>>>(
      WqrT, wkcqb, tmp1, 384, 1536, 1536, 128, 98304, 196608, 8192, nullptr, nullptr);
  reduce1_kernel<<<dim3(512), dim3(256), 0, stream>>>(tmp1, tmpT);
  // fold2: WfoldT[h*64+r][d] = sum_k tmpT[h][r][k] * WqT[d][h*128+k]  (M=64,N=2048,K=128)
  // WfoldT overlays nothing: reuse WqrT? No — write into dedicated region: use hqb? hqb needed.
  // WfoldT lives in prep region: reuse wkcqb (dead after fold1+reduce) -> 4 MiB fits in 6 MiB.
  uint16_t* WfoldT = wkcqb;
  gemm_mfma_kernel<64, 1><<<dim3(1, 16, 16), dim3(256), 0, stream>>>(
      tmpT, WqT, WfoldT, 128, 128, 2048, 2048, 8192, 128, 131072, nullptr, nullptr);
  // qr = rope_q(hqb @ WfoldT^T) [2048][1024], fused rope with log2e-scaled tables
  gemm_mfma_kernel<64, 3><<<dim3(32, 8), dim3(256), 0, stream>>>(hqb, WfoldT, qrb, 2048, 2048,
                                                                 2048, 1024, 0, 0, 0, cosQ, sinQ);
  // kr = rope_k(kvb @ WkrT^T) [2048][1024]
  gemm_mfma_kernel<64, 3><<<dim3(32, 8), dim3(256), 0, stream>>>(kvb, WkrT, krb, 512, 512, 512,
                                                                 1024, 0, 0, 0, cosK, sinK);
  // VhT[b*2048+h*128+kk][l] via EPI=2
  gemm_mfma_kernel<64, 2><<<dim3(32, 16), dim3(256), 0, stream>>>(kvb, wkvb, VhT, 512, 512, 512, 0,
                                                                  0, 0, 0, nullptr, nullptr);
  // flash split over L: 4 partials
  flash3_kernel<<<dim3(32, 16, 4), dim3(256), 0, stream>>>(qrb, krb, VhT, o_part, mlbuf);
  combine_kernel<<<dim3(2048), dim3(256), 0, stream>>>(o_part, mlbuf, ctxlatb);
  // out = ctxlatb @ Wob^T  [2048][2048] f32
  gemm_mfma_kernel<64, 0><<<dim3(32, 16), dim3(256), 0, stream>>>(ctxlatb, Wob, out, 2048, 2048,
                                                                  2048, 2048, 0, 0, 0, nullptr,
                                                                  nullptr);
}

// Round 7
// 163.765 us; speedup vs baseline: 1.0925x; 1.0925x over previous
//
#include <hip/hip_runtime.h>
#include <math.h>
#include <stdint.h>

// Sizes (fixed): B=2, S=L=1024, h=16, k=128, d_c=512, d_cq=1536, r=64, dim_q=2048

typedef __attribute__((ext_vector_type(8))) short short8;
typedef __attribute__((ext_vector_type(4))) float f32x4;

#define GLOAD16(gsrc, ldst)                                                            \
  __builtin_amdgcn_global_load_lds((const __attribute__((address_space(1))) void*)(gsrc), \
                                   (__attribute__((address_space(3))) void*)(ldst), 16, 0, 0)

__device__ inline uint16_t f2b(float x) {  // round-to-nearest-even f32 -> bf16
  uint32_t u = __builtin_bit_cast(uint32_t, x);
  u += 0x7fff + ((u >> 16) & 1);
  return (uint16_t)(u >> 16);
}
__device__ inline float b2f(uint16_t b) {
  uint32_t u = ((uint32_t)b) << 16;
  return __builtin_bit_cast(float, u);
}
__device__ inline uint32_t cvtpk_bf16(float lo, float hi) {  // packs 2 f32 -> 2 bf16 (RNE)
  uint32_t d;
  asm("v_cvt_pk_bf16_f32 %0, %1, %2" : "=v"(d) : "v"(lo), "v"(hi));
  return d;
}

// ---------------- fused f32 -> bf16 convert for 5 buffers (8 el/thread) ----------------
// block counts: hq 2048 | kv 512 | wkv 512 | Wo 2048 | wkcq 1536  (total 6656)
__global__ __launch_bounds__(256) void convert5_kernel(
    const float* __restrict__ s0, uint16_t* __restrict__ t0, const float* __restrict__ s1,
    uint16_t* __restrict__ t1, const float* __restrict__ s2, uint16_t* __restrict__ t2,
    const float* __restrict__ s3, uint16_t* __restrict__ t3, const float* __restrict__ s4,
    uint16_t* __restrict__ t4) {
  int bid = blockIdx.x;
  const float* s;
  uint16_t* t;
  int off;
  if (bid < 2048) { s = s0; t = t0; off = bid; }
  else if (bid < 2560) { s = s1; t = t1; off = bid - 2048; }
  else if (bid < 3072) { s = s2; t = t2; off = bid - 2560; }
  else if (bid < 5120) { s = s3; t = t3; off = bid - 3072; }
  else { s = s4; t = t4; off = bid - 5120; }
  int i = off * 256 + threadIdx.x;
  const float4* s4v = (const float4*)s;
  float4 a = s4v[i * 2], b = s4v[i * 2 + 1];
  union {
    uint16_t u[8];
    uint4 v;
  } o;
  o.u[0] = f2b(a.x); o.u[1] = f2b(a.y); o.u[2] = f2b(a.z); o.u[3] = f2b(a.w);
  o.u[4] = f2b(b.x); o.u[5] = f2b(b.y); o.u[6] = f2b(b.z); o.u[7] = f2b(b.w);
  ((uint4*)t)[i] = o.v;
}

// ---------------- tiled transpose + convert: src f32 [R][C] -> dst bf16 [C][R] ----------------
__global__ __launch_bounds__(256) void transpose_conv_kernel(const float* __restrict__ src,
                                                             uint16_t* __restrict__ dst,
                                                             int R, int C, int sOff, int dOff) {
  __shared__ float t[32][33];
  src += (size_t)blockIdx.z * sOff;
  dst += (size_t)blockIdx.z * dOff;
  int r0 = blockIdx.x * 32, c0 = blockIdx.y * 32;
  int tr = threadIdx.x >> 5, tc = threadIdx.x & 31;
#pragma unroll
  for (int i = 0; i < 4; ++i) t[tr + i * 8][tc] = src[(size_t)(r0 + tr + i * 8) * C + c0 + tc];
  __syncthreads();
#pragma unroll
  for (int i = 0; i < 4; ++i)
    dst[(size_t)(c0 + tr + i * 8) * R + r0 + tc] = f2b(t[tc][tr + i * 8]);
}

// ---------------- rope tables: K-tables plain, Q-tables pre-scaled by log2(e) ----------------
__global__ __launch_bounds__(64) void rope_tables_kernel(float* __restrict__ cosK,
                                                         float* __restrict__ sinK,
                                                         float* __restrict__ cosQ,
                                                         float* __restrict__ sinQ) {
  const float LOG2E = 1.44269504088896341f;
  int s = blockIdx.x;
  int j = threadIdx.x;
  int i = j & 31;
  float inv = powf(10000.0f, -(float)(2 * i) / 64.0f);
  float ang = (float)s * inv;
  float c = cosf(ang), sn = sinf(ang);
  cosK[s * 64 + j] = c;
  sinK[s * 64 + j] = sn;
  cosQ[s * 64 + j] = c * LOG2E;
  sinQ[s * 64 + j] = sn * LOG2E;
}

// ---------------- MFMA GEMM: C[.., M, N] = A[z][M,K]bf16 @ Bt[z][N,K]bf16^T ----------------
// Tile 64 x 128, BK=64, 256 thr (4 waves 2x2), XOR slot swizzle, global_load_lds staging,
// DOUBLE-BUFFERED: next K-tile's loads issued before current tile's compute; 1 barrier/iter.
// EPI 0: f32 row-major; 1: bf16 row-major; 2: bf16 VhT layout; 3: bf16 + fused rope.
// SPLITK>1: z = zh*SPLITK+zk; A/Bt K-offset zk*K; C indexed linearly by z (cZ).
template <int BM, int EPI, int SPLITK = 1>
__global__ __launch_bounds__(256) void gemm_mfma_kernel(const uint16_t* __restrict__ A,
                                                        const uint16_t* __restrict__ Bt,
                                                        void* __restrict__ Cv, int K, int lda,
                                                        int ldb, int ldc, int aZ, int bZ, int cZ,
                                                        const float* __restrict__ rc,
                                                        const float* __restrict__ rs) {
  constexpr int MT = BM / 32;  // m-fragments per wave (2 or 4)
  __shared__ __align__(16) uint16_t As[2][BM * 64];
  __shared__ __align__(16) uint16_t Bs[2][128 * 64];
  int z = blockIdx.z;
  if (SPLITK > 1) {
    int zh = z / SPLITK, zk = z % SPLITK;
    A += (size_t)zh * aZ + (size_t)zk * K;
    Bt += (size_t)zh * bZ + (size_t)zk * K;
  } else {
    A += (size_t)z * aZ;
    Bt += (size_t)z * bZ;
  }
  int m0 = blockIdx.x * BM, n0 = blockIdx.y * 128;
  int tid = threadIdx.x;
  int wave = tid >> 6, lane = tid & 63;
  int wm = wave >> 1, wn = wave & 1;
  int rS = lane >> 3, sl = lane & 7;
  int lr = lane >> 4, lc = lane & 15;

  auto stage = [&](int k0, int buf) {
#pragma unroll
    for (int i = 0; i < MT; ++i) {
      int idx = wave * MT + i;
      int row = idx * 8 + rS;
      GLOAD16(A + (size_t)(m0 + row) * lda + k0 + ((sl ^ (row & 7)) << 3),
              (uint8_t*)As[buf] + idx * 1024);
    }
#pragma unroll
    for (int i = 0; i < 4; ++i) {
      int idx = wave * 4 + i;
      int row = idx * 8 + rS;
      GLOAD16(Bt + (size_t)(n0 + row) * ldb + k0 + ((sl ^ (row & 7)) << 3),
              (uint8_t*)Bs[buf] + idx * 1024);
    }
  };

  f32x4 acc[MT][4] = {};
  stage(0, 0);
  int cur = 0;
  for (int k0 = 0; k0 < K; k0 += 64) {
    __syncthreads();  // drains vmcnt -> buf[cur] ready; prev iter's LDS reads done
    if (k0 + 64 < K) stage(k0 + 64, cur ^ 1);  // prefetch next tile (latency hidden)
    short8 af[MT][2], bf[4][2];
#pragma unroll
    for (int t = 0; t < MT; ++t)
#pragma unroll
      for (int ks = 0; ks < 2; ++ks) {
        int slot = ks * 4 + lr;
        int ra = wm * (BM / 2) + t * 16 + lc;
        af[t][ks] =
            *(const short8*)((const uint8_t*)As[cur] + ra * 128 + ((slot ^ (ra & 7)) << 4));
      }
#pragma unroll
    for (int t = 0; t < 4; ++t)
#pragma unroll
      for (int ks = 0; ks < 2; ++ks) {
        int slot = ks * 4 + lr;
        int rb = wn * 64 + t * 16 + lc;
        bf[t][ks] =
            *(const short8*)((const uint8_t*)Bs[cur] + rb * 128 + ((slot ^ (rb & 7)) << 4));
      }
    __builtin_amdgcn_s_setprio(1);
#pragma unroll
    for (int mt = 0; mt < MT; ++mt)
#pragma unroll
      for (int nt = 0; nt < 4; ++nt) {
        acc[mt][nt] =
            __builtin_amdgcn_mfma_f32_16x16x32_bf16(af[mt][0], bf[nt][0], acc[mt][nt], 0, 0, 0);
        acc[mt][nt] =
            __builtin_amdgcn_mfma_f32_16x16x32_bf16(af[mt][1], bf[nt][1], acc[mt][nt], 0, 0, 0);
      }
    __builtin_amdgcn_s_setprio(0);
    cur ^= 1;
  }
  if (EPI == 3) {
#pragma unroll
    for (int mt = 0; mt < MT; ++mt)
#pragma unroll
      for (int nt = 0; nt < 4; ++nt)
#pragma unroll
        for (int r = 0; r < 4; ++r) {
          int m = m0 + wm * (BM / 2) + mt * 16 + lr * 4 + r;
          int n = n0 + wn * 64 + nt * 16 + lc;
          int pos = m & 1023, j = n & 63;
          float x = acc[mt][nt][r];
          float prt = acc[mt][nt ^ 2][r];
          float rot = (nt & 2) ? prt : -prt;
          float v = fmaf(x, rc[pos * 64 + j], rot * rs[pos * 64 + j]);
          ((uint16_t*)Cv)[(size_t)m * ldc + n] = f2b(v);
        }
  } else {
#pragma unroll
    for (int mt = 0; mt < MT; ++mt)
#pragma unroll
      for (int nt = 0; nt < 4; ++nt)
#pragma unroll
        for (int r = 0; r < 4; ++r) {
          int m = m0 + wm * (BM / 2) + mt * 16 + lr * 4 + r;
          int n = n0 + wn * 64 + nt * 16 + lc;
          float v = acc[mt][nt][r];
          if (EPI == 0)
            ((float*)Cv)[(size_t)z * cZ + (size_t)m * ldc + n] = v;
          else if (EPI == 1)
            ((uint16_t*)Cv)[(size_t)z * cZ + (size_t)m * ldc + n] = f2b(v);
          else
            ((uint16_t*)Cv)[((size_t)((m >> 10) * 2048 + n)) * 1024 + (m & 1023)] = f2b(v);
        }
  }
}

// ---------------- reduce fold1 split-K partials f32 -> bf16 ----------------
// tp: [16 heads][4 splits][8192], out: [16][8192] bf16
__global__ __launch_bounds__(256) void reduce1_kernel(const float* __restrict__ tp,
                                                      uint16_t* __restrict__ tmpT) {
  int gid = blockIdx.x * 256 + threadIdx.x;  // 131072
  int zh = gid >> 13, e = gid & 8191;
  const float* b = tp + (size_t)zh * 32768 + e;
  tmpT[gid] = f2b(b[0] + b[8192] + b[16384] + b[24576]);
}

// ---------------- MFMA flash attention (exp2 domain; q pre-scaled by log2e) ----------------
// grid (bh=32, stile=16), 256 thr = 4 waves; wave owns 16 q-rows. DOUBLE-BUFFERED K/V staging.
// Out: ctxlatb bf16 [b*1024+s][2048]
__global__ __launch_bounds__(256) void flash3_kernel(const uint16_t* __restrict__ qrb,
                                                     const uint16_t* __restrict__ krb,
                                                     const uint16_t* __restrict__ VhT,
                                                     uint16_t* __restrict__ ctxlatb) {
  __shared__ __align__(16) uint16_t Ks[2][64 * 64];   // rows l, 64 r (128B, swizzled)
  __shared__ __align__(16) uint16_t Vs[2][128 * 64];  // rows kk, 64 l (128B, swizzled)
  __shared__ __align__(16) uint16_t Ps[4][16 * 64];   // per-wave P, swizzled
  int bh = blockIdx.x;
  int b = bh >> 4, h = bh & 15;
  int s0 = blockIdx.y * 64;
  int tid = threadIdx.x, wave = tid >> 6, lane = tid & 63;
  int lr = lane >> 4, lc = lane & 15;
  int rS = lane >> 3, sl = lane & 7;

  const uint16_t* qrow = qrb + (size_t)(b * 1024 + s0 + wave * 16 + lc) * 1024 + h * 64;
  short8 qa[2];
  qa[0] = *(const short8*)(qrow + lr * 8);
  qa[1] = *(const short8*)(qrow + 32 + lr * 8);

  float m_run[4], l_run[4];
#pragma unroll
  for (int r = 0; r < 4; ++r) {
    m_run[r] = -1e30f;
    l_run[r] = 0.f;
  }
  f32x4 o[8] = {};

  const uint16_t* krbase = krb + (size_t)(b * 1024) * 1024 + h * 64;
  const uint16_t* vtbase = VhT + (size_t)(b * 2048 + h * 128) * 1024;

  auto stageKV = [&](int l0, int buf) {
#pragma unroll
    for (int i = 0; i < 2; ++i) {  // K tile: 8KB
      int idx = wave * 2 + i;
      int row = idx * 8 + rS;
      GLOAD16(krbase + (size_t)(l0 + row) * 1024 + ((sl ^ (row & 7)) << 3),
              (uint8_t*)Ks[buf] + idx * 1024);
    }
#pragma unroll
    for (int i = 0; i < 4; ++i) {  // V^T tile: 16KB
      int idx = wave * 4 + i;
      int row = idx * 8 + rS;
      GLOAD16(vtbase + (size_t)row * 1024 + l0 + ((sl ^ (row & 7)) << 3),
              (uint8_t*)Vs[buf] + idx * 1024);
    }
  };

  stageKV(0, 0);
  int cur = 0;
  for (int l0 = 0; l0 < 1024; l0 += 64) {
    __syncthreads();  // buf[cur] staged; prev iter's LDS reads complete
    if (l0 + 64 < 1024) stageKV(l0 + 64, cur ^ 1);  // prefetch next tile under compute

    // QK^T: sc[nt] covers cols nt*16+lc, rows lr*4+r   (log2 domain; q pre-scaled)
    f32x4 sc[4];
    __builtin_amdgcn_s_setprio(1);
#pragma unroll
    for (int nt = 0; nt < 4; ++nt) {
      int rowk = nt * 16 + lc;
      short8 kb0 =
          *(const short8*)((const uint8_t*)Ks[cur] + rowk * 128 + ((lr ^ (rowk & 7)) << 4));
      short8 kb1 =
          *(const short8*)((const uint8_t*)Ks[cur] + rowk * 128 + (((4 + lr) ^ (rowk & 7)) << 4));
      f32x4 z = {};
      z = __builtin_amdgcn_mfma_f32_16x16x32_bf16(qa[0], kb0, z, 0, 0, 0);
      sc[nt] = __builtin_amdgcn_mfma_f32_16x16x32_bf16(qa[1], kb1, z, 0, 0, 0);
    }
    __builtin_amdgcn_s_setprio(0);

    // per-row tile max (16-lane reduce)
    float mx[4];
#pragma unroll
    for (int r = 0; r < 4; ++r) {
      float m = fmaxf(fmaxf(sc[0][r], sc[1][r]), fmaxf(sc[2][r], sc[3][r]));
      m = fmaxf(m, __shfl_xor(m, 1));
      m = fmaxf(m, __shfl_xor(m, 2));
      m = fmaxf(m, __shfl_xor(m, 4));
      mx[r] = fmaxf(m, __shfl_xor(m, 8));
    }
    // defer-max: skip rescale when all rows grew <= 8 (log2 domain -> P <= 256)
    bool grow = false;
#pragma unroll
    for (int r = 0; r < 4; ++r) grow |= (mx[r] > m_run[r] + 8.0f);
    bool upd = (__ballot(grow) != 0ULL);  // wave-uniform
    float scale[4];
    if (upd) {
#pragma unroll
      for (int r = 0; r < 4; ++r) {
        float mn = fmaxf(m_run[r], mx[r]);
        scale[r] = exp2f(m_run[r] - mn);
        m_run[r] = mn;
      }
    }
    float ps[4] = {0.f, 0.f, 0.f, 0.f};
#pragma unroll
    for (int nt = 0; nt < 4; ++nt) {
      int pcol = nt * 16 + lc;
#pragma unroll
      for (int rp = 0; rp < 2; ++rp) {
        float p0 = exp2f(sc[nt][rp * 2] - m_run[rp * 2]);
        float p1 = exp2f(sc[nt][rp * 2 + 1] - m_run[rp * 2 + 1]);
        ps[rp * 2] += p0;
        ps[rp * 2 + 1] += p1;
        uint32_t u = cvtpk_bf16(p0, p1);
        int prow0 = lr * 4 + rp * 2;
        uint32_t a0 = prow0 * 128 + ((((pcol >> 3) ^ (prow0 & 7))) << 4) + (pcol & 7) * 2;
        int prow1 = prow0 + 1;
        uint32_t a1 = prow1 * 128 + ((((pcol >> 3) ^ (prow1 & 7))) << 4) + (pcol & 7) * 2;
        *(uint16_t*)((uint8_t*)Ps[wave] + a0) = (uint16_t)u;
        *(uint16_t*)((uint8_t*)Ps[wave] + a1) = (uint16_t)(u >> 16);
      }
    }
#pragma unroll
    for (int r = 0; r < 4; ++r) {
      float s = ps[r];
      s += __shfl_xor(s, 1);
      s += __shfl_xor(s, 2);
      s += __shfl_xor(s, 4);
      s += __shfl_xor(s, 8);
      ps[r] = s;
    }
    if (upd) {
#pragma unroll
      for (int r = 0; r < 4; ++r) l_run[r] = l_run[r] * scale[r] + ps[r];
#pragma unroll
      for (int nt = 0; nt < 8; ++nt)
#pragma unroll
        for (int r = 0; r < 4; ++r) o[nt][r] *= scale[r];
    } else {
#pragma unroll
      for (int r = 0; r < 4; ++r) l_run[r] += ps[r];
    }

    // P as A-fragment (wave-local LDS bounce; compiler inserts lgkmcnt)
    short8 pa[2];
#pragma unroll
    for (int ks = 0; ks < 2; ++ks) {
      int slot = ks * 4 + lr;
      pa[ks] = *(const short8*)((const uint8_t*)Ps[wave] + lc * 128 + ((slot ^ (lc & 7)) << 4));
    }
    // PV: o[nt] covers kk cols nt*16+lc
    __builtin_amdgcn_s_setprio(1);
#pragma unroll
    for (int nt = 0; nt < 8; ++nt) {
      int rowv = nt * 16 + lc;
      short8 vb0 =
          *(const short8*)((const uint8_t*)Vs[cur] + rowv * 128 + ((lr ^ (rowv & 7)) << 4));
      short8 vb1 =
          *(const short8*)((const uint8_t*)Vs[cur] + rowv * 128 + (((4 + lr) ^ (rowv & 7)) << 4));
      o[nt] = __builtin_amdgcn_mfma_f32_16x16x32_bf16(pa[0], vb0, o[nt], 0, 0, 0);
      o[nt] = __builtin_amdgcn_mfma_f32_16x16x32_bf16(pa[1], vb1, o[nt], 0, 0, 0);
    }
    __builtin_amdgcn_s_setprio(0);
    cur ^= 1;
  }
  // epilogue
  uint16_t* orow = ctxlatb + (size_t)(b * 1024 + s0 + wave * 16) * 2048 + h * 128;
#pragma unroll
  for (int nt = 0; nt < 8; ++nt)
#pragma unroll
    for (int r = 0; r < 4; ++r)
      orow[(size_t)(lr * 4 + r) * 2048 + nt * 16 + lc] = f2b(o[nt][r] / l_run[r]);
}

extern "C" void kernel_launch(void* const* d_in, const int* in_sizes, int n_in,
                              void* d_out, int out_size, void* d_ws, size_t ws_size,
                              hipStream_t stream) {
  const float* hidden_q = (const float*)d_in[0];
  const float* kv_c = (const float*)d_in[1];
  const float* Wq = (const float*)d_in[2];
  const float* w_kc_q = (const float*)d_in[3];
  const float* W_qr = (const float*)d_in[4];
  const float* W_kr = (const float*)d_in[5];
  const float* w_kc_kv = (const float*)d_in[6];
  const float* Wo = (const float*)d_in[7];
  float* out = (float*)d_out;

  const size_t MB = 1024 * 1024;
  uint8_t* base = (uint8_t*)d_ws;
  // --- live through flash ---
  uint16_t* Wob = (uint16_t*)(base + 0 * MB);       // 8 MiB
  uint16_t* qrb = (uint16_t*)(base + 8 * MB);       // 4 MiB [2048][1024] (q pre-scaled log2e)
  uint16_t* krb = (uint16_t*)(base + 12 * MB);      // 4 MiB [2048][1024]
  uint16_t* VhT = (uint16_t*)(base + 16 * MB);      // 8 MiB [b*2048+h*128+kk][1024]
  uint16_t* ctxlatb = (uint16_t*)(base + 24 * MB);  // 8 MiB [b*1024+s][2048]
  // --- prep stage (dead by flash time) ---
  float* cosK = (float*)(base + 32 * MB);
  float* sinK = (float*)(base + 32 * MB + 262144);
  float* cosQ = (float*)(base + 32 * MB + 524288);
  float* sinQ = (float*)(base + 32 * MB + 786432);
  uint16_t* hqb = (uint16_t*)(base + 33 * MB);      // 8 MiB
  uint16_t* kvb = (uint16_t*)(base + 41 * MB);      // 2 MiB
  uint16_t* wkvb = (uint16_t*)(base + 43 * MB);     // 2 MiB
  uint16_t* WqT = (uint16_t*)(base + 45 * MB);      // 8 MiB
  uint16_t* WqrT = (uint16_t*)(base + 53 * MB);     // 3 MiB
  uint16_t* wkcqb = (uint16_t*)(base + 56 * MB);    // 6 MiB
  float* tmp1 = (float*)(base + 62 * MB);           // 2 MiB f32 fold1 partials [16][4][8192]
  uint16_t* tmpT = (uint16_t*)(base + 64 * MB);     // 256 KiB
  uint16_t* WkrT = (uint16_t*)(base + 64 * MB + 262144);  // 1 MiB

  convert5_kernel<<<dim3(6656), dim3(256), 0, stream>>>(hidden_q, hqb, kv_c, kvb, w_kc_kv, wkvb,
                                                        Wo, Wob, w_kc_q, wkcqb);
  rope_tables_kernel<<<dim3(1024), dim3(64), 0, stream>>>(cosK, sinK, cosQ, sinQ);
  // W_qr [h][1536][64] -> WqrT [h][64][1536]
  transpose_conv_kernel<<<dim3(48, 2, 16), dim3(256), 0, stream>>>((const float*)W_qr, WqrT, 1536,
                                                                   64, 98304, 98304);
  // Wq [2048][2048] -> WqT [2048][2048]
  transpose_conv_kernel<<<dim3(64, 64, 1), dim3(256), 0, stream>>>(Wq, WqT, 2048, 2048, 0, 0);
  // W_kr [h][512][64] -> WkrT [h][64][512]
  transpose_conv_kernel<<<dim3(16, 2, 16), dim3(256), 0, stream>>>((const float*)W_kr, WkrT, 512,
                                                                   64, 32768, 32768);
  // fold1 split-K x4: tmp1[h*4+zk] = partial sum over q in [zk*384,(zk+1)*384)
  gemm_mfma_kernel<64, 0, 4><<<dim3(1, 1, 64), dim3(256), 0, stream>>>(
      WqrT, wkcqb, tmp1, 384, 1536, 1536, 128, 98304, 196608, 8192, nullptr, nullptr);
  reduce1_kernel<<<dim3(512), dim3(256), 0, stream>>>(tmp1, tmpT);
  // fold2: WfoldT[h*64+r][d] = sum_k tmpT[h][r][k] * WqT[d][h*128+k]  (M=64,N=2048,K=128)
  // WfoldT overlays wkcqb (dead after fold1+reduce)
  uint16_t* WfoldT = wkcqb;
  gemm_mfma_kernel<64, 1><<<dim3(1, 16, 16), dim3(256), 0, stream>>>(
      tmpT, WqT, WfoldT, 128, 128, 2048, 2048, 8192, 128, 131072, nullptr, nullptr);
  // qr = rope_q(hqb @ WfoldT^T) [2048][1024], fused rope with log2e-scaled tables
  gemm_mfma_kernel<64, 3><<<dim3(32, 8), dim3(256), 0, stream>>>(hqb, WfoldT, qrb, 2048, 2048,
                                                                 2048, 1024, 0, 0, 0, cosQ, sinQ);
  // kr = rope_k(kvb @ WkrT^T) [2048][1024]
  gemm_mfma_kernel<64, 3><<<dim3(32, 8), dim3(256), 0, stream>>>(kvb, WkrT, krb, 512, 512, 512,
                                                                 1024, 0, 0, 0, cosK, sinK);
  // VhT[b*2048+h*128+kk][l] via EPI=2
  gemm_mfma_kernel<64, 2><<<dim3(32, 16), dim3(256), 0, stream>>>(kvb, wkvb, VhT, 512, 512, 512, 0,
                                                                  0, 0, 0, nullptr, nullptr);
  // fused flash attention -> ctxlatb
  flash3_kernel<<<dim3(32, 16), dim3(256), 0, stream>>>(qrb, krb, VhT, ctxlatb);
  // out = ctxlatb @ Wob^T  [2048][2048] f32
  gemm_mfma_kernel<64, 0><<<dim3(32, 16), dim3(256), 0, stream>>>(ctxlatb, Wob, out, 2048, 2048,
                                                                  2048, 2048, 0, 0, 0, nullptr,
                                                                  nullptr);
}

// Round 8
// 153.113 us; speedup vs baseline: 1.1685x; 1.0696x over previous
//
#include <hip/hip_runtime.h>
#include <math.h>
#include <stdint.h>

// Sizes (fixed): B=2, S=L=1024, h=16, k=128, d_c=512, d_cq=1536, r=64, dim_q=2048

typedef __attribute__((ext_vector_type(8))) short short8;
typedef __attribute__((ext_vector_type(4))) float f32x4;

#define GLOAD16(gsrc, ldst)                                                            \
  __builtin_amdgcn_global_load_lds((const __attribute__((address_space(1))) void*)(gsrc), \
                                   (__attribute__((address_space(3))) void*)(ldst), 16, 0, 0)

__device__ inline uint16_t f2b(float x) {  // round-to-nearest-even f32 -> bf16
  uint32_t u = __builtin_bit_cast(uint32_t, x);
  u += 0x7fff + ((u >> 16) & 1);
  return (uint16_t)(u >> 16);
}
__device__ inline float b2f(uint16_t b) {
  uint32_t u = ((uint32_t)b) << 16;
  return __builtin_bit_cast(float, u);
}
__device__ inline uint32_t cvtpk_bf16(float lo, float hi) {  // packs 2 f32 -> 2 bf16 (RNE)
  uint32_t d;
  asm("v_cvt_pk_bf16_f32 %0, %1, %2" : "=v"(d) : "v"(lo), "v"(hi));
  return d;
}

// ---------------- fused f32 -> bf16 convert for 5 buffers (8 el/thread) ----------------
// block counts: hq 2048 | kv 512 | wkv 512 | Wo 2048 | wkcq 1536  (total 6656)
__global__ __launch_bounds__(256) void convert5_kernel(
    const float* __restrict__ s0, uint16_t* __restrict__ t0, const float* __restrict__ s1,
    uint16_t* __restrict__ t1, const float* __restrict__ s2, uint16_t* __restrict__ t2,
    const float* __restrict__ s3, uint16_t* __restrict__ t3, const float* __restrict__ s4,
    uint16_t* __restrict__ t4) {
  int bid = blockIdx.x;
  const float* s;
  uint16_t* t;
  int off;
  if (bid < 2048) { s = s0; t = t0; off = bid; }
  else if (bid < 2560) { s = s1; t = t1; off = bid - 2048; }
  else if (bid < 3072) { s = s2; t = t2; off = bid - 2560; }
  else if (bid < 5120) { s = s3; t = t3; off = bid - 3072; }
  else { s = s4; t = t4; off = bid - 5120; }
  int i = off * 256 + threadIdx.x;
  const float4* s4v = (const float4*)s;
  float4 a = s4v[i * 2], b = s4v[i * 2 + 1];
  union {
    uint16_t u[8];
    uint4 v;
  } o;
  o.u[0] = f2b(a.x); o.u[1] = f2b(a.y); o.u[2] = f2b(a.z); o.u[3] = f2b(a.w);
  o.u[4] = f2b(b.x); o.u[5] = f2b(b.y); o.u[6] = f2b(b.z); o.u[7] = f2b(b.w);
  ((uint4*)t)[i] = o.v;
}

// ---------------- tiled transpose + convert: src f32 [R][C] -> dst bf16 [C][R] ----------------
__global__ __launch_bounds__(256) void transpose_conv_kernel(const float* __restrict__ src,
                                                             uint16_t* __restrict__ dst,
                                                             int R, int C, int sOff, int dOff) {
  __shared__ float t[32][33];
  src += (size_t)blockIdx.z * sOff;
  dst += (size_t)blockIdx.z * dOff;
  int r0 = blockIdx.x * 32, c0 = blockIdx.y * 32;
  int tr = threadIdx.x >> 5, tc = threadIdx.x & 31;
#pragma unroll
  for (int i = 0; i < 4; ++i) t[tr + i * 8][tc] = src[(size_t)(r0 + tr + i * 8) * C + c0 + tc];
  __syncthreads();
#pragma unroll
  for (int i = 0; i < 4; ++i)
    dst[(size_t)(c0 + tr + i * 8) * R + r0 + tc] = f2b(t[tc][tr + i * 8]);
}

// ---------------- rope tables: K-tables plain, Q-tables pre-scaled by log2(e) ----------------
__global__ __launch_bounds__(64) void rope_tables_kernel(float* __restrict__ cosK,
                                                         float* __restrict__ sinK,
                                                         float* __restrict__ cosQ,
                                                         float* __restrict__ sinQ) {
  const float LOG2E = 1.44269504088896341f;
  int s = blockIdx.x;
  int j = threadIdx.x;
  int i = j & 31;
  float inv = powf(10000.0f, -(float)(2 * i) / 64.0f);
  float ang = (float)s * inv;
  float c = cosf(ang), sn = sinf(ang);
  cosK[s * 64 + j] = c;
  sinK[s * 64 + j] = sn;
  cosQ[s * 64 + j] = c * LOG2E;
  sinQ[s * 64 + j] = sn * LOG2E;
}

// ---------------- MFMA GEMM: C[.., M, N] = A[z][M,K]bf16 @ Bt[z][N,K]bf16^T ----------------
// Tile BM x 128, BK=64, 256 thr (4 waves 2x2), XOR slot swizzle, global_load_lds staging,
// DOUBLE-BUFFERED: next K-tile's loads issued before current tile's compute; 1 barrier/iter.
// EPI 0: f32 row-major; 1: bf16 row-major; 2: bf16 VhT layout; 3: bf16 + fused rope.
// SPLITK>1: z = zh*SPLITK+zk; A/Bt K-offset zk*K; C indexed linearly by z (cZ).
template <int BM, int EPI, int SPLITK = 1>
__global__ __launch_bounds__(256) void gemm_mfma_kernel(const uint16_t* __restrict__ A,
                                                        const uint16_t* __restrict__ Bt,
                                                        void* __restrict__ Cv, int K, int lda,
                                                        int ldb, int ldc, int aZ, int bZ, int cZ,
                                                        const float* __restrict__ rc,
                                                        const float* __restrict__ rs) {
  constexpr int MT = BM / 32;  // m-fragments per wave (2 or 4)
  __shared__ __align__(16) uint16_t As[2][BM * 64];
  __shared__ __align__(16) uint16_t Bs[2][128 * 64];
  int z = blockIdx.z;
  if (SPLITK > 1) {
    int zh = z / SPLITK, zk = z % SPLITK;
    A += (size_t)zh * aZ + (size_t)zk * K;
    Bt += (size_t)zh * bZ + (size_t)zk * K;
  } else {
    A += (size_t)z * aZ;
    Bt += (size_t)z * bZ;
  }
  int m0 = blockIdx.x * BM, n0 = blockIdx.y * 128;
  int tid = threadIdx.x;
  int wave = tid >> 6, lane = tid & 63;
  int wm = wave >> 1, wn = wave & 1;
  int rS = lane >> 3, sl = lane & 7;
  int lr = lane >> 4, lc = lane & 15;

  auto stage = [&](int k0, int buf) {
#pragma unroll
    for (int i = 0; i < MT; ++i) {
      int idx = wave * MT + i;
      int row = idx * 8 + rS;
      GLOAD16(A + (size_t)(m0 + row) * lda + k0 + ((sl ^ (row & 7)) << 3),
              (uint8_t*)As[buf] + idx * 1024);
    }
#pragma unroll
    for (int i = 0; i < 4; ++i) {
      int idx = wave * 4 + i;
      int row = idx * 8 + rS;
      GLOAD16(Bt + (size_t)(n0 + row) * ldb + k0 + ((sl ^ (row & 7)) << 3),
              (uint8_t*)Bs[buf] + idx * 1024);
    }
  };

  f32x4 acc[MT][4] = {};
  stage(0, 0);
  int cur = 0;
  for (int k0 = 0; k0 < K; k0 += 64) {
    __syncthreads();  // drains vmcnt -> buf[cur] ready; prev iter's LDS reads done
    if (k0 + 64 < K) stage(k0 + 64, cur ^ 1);  // prefetch next tile (latency hidden)
    short8 af[MT][2], bf[4][2];
#pragma unroll
    for (int t = 0; t < MT; ++t)
#pragma unroll
      for (int ks = 0; ks < 2; ++ks) {
        int slot = ks * 4 + lr;
        int ra = wm * (BM / 2) + t * 16 + lc;
        af[t][ks] =
            *(const short8*)((const uint8_t*)As[cur] + ra * 128 + ((slot ^ (ra & 7)) << 4));
      }
#pragma unroll
    for (int t = 0; t < 4; ++t)
#pragma unroll
      for (int ks = 0; ks < 2; ++ks) {
        int slot = ks * 4 + lr;
        int rb = wn * 64 + t * 16 + lc;
        bf[t][ks] =
            *(const short8*)((const uint8_t*)Bs[cur] + rb * 128 + ((slot ^ (rb & 7)) << 4));
      }
    __builtin_amdgcn_s_setprio(1);
#pragma unroll
    for (int mt = 0; mt < MT; ++mt)
#pragma unroll
      for (int nt = 0; nt < 4; ++nt) {
        acc[mt][nt] =
            __builtin_amdgcn_mfma_f32_16x16x32_bf16(af[mt][0], bf[nt][0], acc[mt][nt], 0, 0, 0);
        acc[mt][nt] =
            __builtin_amdgcn_mfma_f32_16x16x32_bf16(af[mt][1], bf[nt][1], acc[mt][nt], 0, 0, 0);
      }
    __builtin_amdgcn_s_setprio(0);
    cur ^= 1;
  }
  if (EPI == 3) {
#pragma unroll
    for (int mt = 0; mt < MT; ++mt)
#pragma unroll
      for (int nt = 0; nt < 4; ++nt)
#pragma unroll
        for (int r = 0; r < 4; ++r) {
          int m = m0 + wm * (BM / 2) + mt * 16 + lr * 4 + r;
          int n = n0 + wn * 64 + nt * 16 + lc;
          int pos = m & 1023, j = n & 63;
          float x = acc[mt][nt][r];
          float prt = acc[mt][nt ^ 2][r];
          float rot = (nt & 2) ? prt : -prt;
          float v = fmaf(x, rc[pos * 64 + j], rot * rs[pos * 64 + j]);
          ((uint16_t*)Cv)[(size_t)m * ldc + n] = f2b(v);
        }
  } else {
#pragma unroll
    for (int mt = 0; mt < MT; ++mt)
#pragma unroll
      for (int nt = 0; nt < 4; ++nt)
#pragma unroll
        for (int r = 0; r < 4; ++r) {
          int m = m0 + wm * (BM / 2) + mt * 16 + lr * 4 + r;
          int n = n0 + wn * 64 + nt * 16 + lc;
          float v = acc[mt][nt][r];
          if (EPI == 0)
            ((float*)Cv)[(size_t)z * cZ + (size_t)m * ldc + n] = v;
          else if (EPI == 1)
            ((uint16_t*)Cv)[(size_t)z * cZ + (size_t)m * ldc + n] = f2b(v);
          else
            ((uint16_t*)Cv)[((size_t)((m >> 10) * 2048 + n)) * 1024 + (m & 1023)] = f2b(v);
        }
  }
}

// ---------------- reduce fold1 split-K partials f32 -> bf16 ----------------
// tp: [16 heads][4 splits][8192], out: [16][8192] bf16
__global__ __launch_bounds__(256) void reduce1_kernel(const float* __restrict__ tp,
                                                      uint16_t* __restrict__ tmpT) {
  int gid = blockIdx.x * 256 + threadIdx.x;  // 131072
  int zh = gid >> 13, e = gid & 8191;
  const float* b = tp + (size_t)zh * 32768 + e;
  tmpT[gid] = f2b(b[0] + b[8192] + b[16384] + b[24576]);
}

// ---------------- MFMA flash attention, SWAPPED QK^T (scores transposed: lane = q-row) -------
// grid (bh=32, stile=16), 256 thr = 4 waves; wave owns 16 q-rows. Double-buffered K/V staging.
// exp2 domain (q pre-scaled by log2e). Out: ctxlatb bf16 [b*1024+s][2048]
__global__ __launch_bounds__(256) void flash3_kernel(const uint16_t* __restrict__ qrb,
                                                     const uint16_t* __restrict__ krb,
                                                     const uint16_t* __restrict__ VhT,
                                                     uint16_t* __restrict__ ctxlatb) {
  __shared__ __align__(16) uint16_t Ks[2][64 * 64];   // rows l, 64 r (128B, swizzled)
  __shared__ __align__(16) uint16_t Vs[2][128 * 64];  // rows kk, 64 l (128B, swizzled)
  __shared__ __align__(16) uint8_t Ps[4][16 * 144];   // per-wave P [q-row][64 k, stride 144B]
  int bh = blockIdx.x;
  int b = bh >> 4, h = bh & 15;
  int s0 = blockIdx.y * 64;
  int tid = threadIdx.x, wave = tid >> 6, lane = tid & 63;
  int lr = lane >> 4, lc = lane & 15;
  int rS = lane >> 3, sl = lane & 7;

  const uint16_t* qrow = qrb + (size_t)(b * 1024 + s0 + wave * 16 + lc) * 1024 + h * 64;
  short8 qa[2];
  qa[0] = *(const short8*)(qrow + lr * 8);
  qa[1] = *(const short8*)(qrow + 32 + lr * 8);

  // per-lane softmax state for q-row lc (lanes in an lr-group hold identical copies)
  float m_run = -1e30f, l_run = 0.f;
  f32x4 o[8] = {};

  // P LDS addressing: store base (u32 at +nt*32+rp*4), read base (b128 at +ks*64)
  uint8_t* psW = Ps[wave] + lc * 144 + lr * 8;
  const uint8_t* psR = Ps[wave] + lc * 144 + lr * 16;

  const uint16_t* krbase = krb + (size_t)(b * 1024) * 1024 + h * 64;
  const uint16_t* vtbase = VhT + (size_t)(b * 2048 + h * 128) * 1024;

  auto stageKV = [&](int l0, int buf) {
#pragma unroll
    for (int i = 0; i < 2; ++i) {  // K tile: 8KB
      int idx = wave * 2 + i;
      int row = idx * 8 + rS;
      GLOAD16(krbase + (size_t)(l0 + row) * 1024 + ((sl ^ (row & 7)) << 3),
              (uint8_t*)Ks[buf] + idx * 1024);
    }
#pragma unroll
    for (int i = 0; i < 4; ++i) {  // V^T tile: 16KB
      int idx = wave * 4 + i;
      int row = idx * 8 + rS;
      GLOAD16(vtbase + (size_t)row * 1024 + l0 + ((sl ^ (row & 7)) << 3),
              (uint8_t*)Vs[buf] + idx * 1024);
    }
  };

  stageKV(0, 0);
  int cur = 0;
  for (int l0 = 0; l0 < 1024; l0 += 64) {
    __syncthreads();  // buf[cur] staged; prev iter's LDS reads complete
    if (l0 + 64 < 1024) stageKV(l0 + 64, cur ^ 1);  // prefetch next tile under compute

    // QK^T swapped: sc[nt] rows = k (nt*16 + lr*4+r), col = q-row (lc)
    f32x4 sc[4];
    __builtin_amdgcn_s_setprio(1);
#pragma unroll
    for (int nt = 0; nt < 4; ++nt) {
      int rowk = nt * 16 + lc;
      short8 kb0 =
          *(const short8*)((const uint8_t*)Ks[cur] + rowk * 128 + ((lr ^ (rowk & 7)) << 4));
      short8 kb1 =
          *(const short8*)((const uint8_t*)Ks[cur] + rowk * 128 + (((4 + lr) ^ (rowk & 7)) << 4));
      f32x4 z = {};
      z = __builtin_amdgcn_mfma_f32_16x16x32_bf16(kb0, qa[0], z, 0, 0, 0);
      sc[nt] = __builtin_amdgcn_mfma_f32_16x16x32_bf16(kb1, qa[1], z, 0, 0, 0);
    }
    __builtin_amdgcn_s_setprio(0);

    // lane-local max over 16 k-values, then 2-shuffle reduce across lr-group
    float mx = fmaxf(fmaxf(fmaxf(sc[0][0], sc[0][1]), fmaxf(sc[0][2], sc[0][3])),
                     fmaxf(fmaxf(sc[1][0], sc[1][1]), fmaxf(sc[1][2], sc[1][3])));
    float mx2 = fmaxf(fmaxf(fmaxf(sc[2][0], sc[2][1]), fmaxf(sc[2][2], sc[2][3])),
                      fmaxf(fmaxf(sc[3][0], sc[3][1]), fmaxf(sc[3][2], sc[3][3])));
    mx = fmaxf(mx, mx2);
    mx = fmaxf(mx, __shfl_xor(mx, 16));
    mx = fmaxf(mx, __shfl_xor(mx, 32));

    // defer-max: skip rescale when max grew <= 8 (log2 domain -> P <= 256)
    bool grow = mx > m_run + 8.0f;
    bool upd = (__ballot(grow) != 0ULL);  // wave-uniform
    float scale;
    if (upd) {
      float mn = fmaxf(m_run, mx);
      scale = exp2f(m_run - mn);
      m_run = mn;
    }

    // P = exp2(sc - m), packed bf16 stores at base + immediate (k = nt*16+lr*4+rp*2)
    float ps = 0.f;
#pragma unroll
    for (int nt = 0; nt < 4; ++nt) {
#pragma unroll
      for (int rp = 0; rp < 2; ++rp) {
        float p0 = exp2f(sc[nt][rp * 2] - m_run);
        float p1 = exp2f(sc[nt][rp * 2 + 1] - m_run);
        ps += p0 + p1;
        *(uint32_t*)(psW + nt * 32 + rp * 4) = cvtpk_bf16(p0, p1);
      }
    }
    ps += __shfl_xor(ps, 16);
    ps += __shfl_xor(ps, 32);

    if (upd) {
      l_run = l_run * scale + ps;
      // transport scale from lane-domain (q=lc) to o-row-domain (q=lr*4+r)
      float s0 = __shfl(scale, lr * 4 + 0);
      float s1 = __shfl(scale, lr * 4 + 1);
      float s2 = __shfl(scale, lr * 4 + 2);
      float s3 = __shfl(scale, lr * 4 + 3);
#pragma unroll
      for (int nt = 0; nt < 8; ++nt) {
        o[nt][0] *= s0;
        o[nt][1] *= s1;
        o[nt][2] *= s2;
        o[nt][3] *= s3;
      }
    } else {
      l_run += ps;
    }

    // P as A-fragment (row = q = lc, k elems ks*32 + lr*8): 2 reads at base + immediate
    short8 pa[2];
    pa[0] = *(const short8*)(psR);
    pa[1] = *(const short8*)(psR + 64);
    // PV: o[nt] rows = q (lr*4+r), col = kk (nt*16+lc)
    __builtin_amdgcn_s_setprio(1);
#pragma unroll
    for (int nt = 0; nt < 8; ++nt) {
      int rowv = nt * 16 + lc;
      short8 vb0 =
          *(const short8*)((const uint8_t*)Vs[cur] + rowv * 128 + ((lr ^ (rowv & 7)) << 4));
      short8 vb1 =
          *(const short8*)((const uint8_t*)Vs[cur] + rowv * 128 + (((4 + lr) ^ (rowv & 7)) << 4));
      o[nt] = __builtin_amdgcn_mfma_f32_16x16x32_bf16(pa[0], vb0, o[nt], 0, 0, 0);
      o[nt] = __builtin_amdgcn_mfma_f32_16x16x32_bf16(pa[1], vb1, o[nt], 0, 0, 0);
    }
    __builtin_amdgcn_s_setprio(0);
    cur ^= 1;
  }
  // epilogue: l_run lives in lane-domain (q=lc); fetch for this thread's 4 o-rows
  float li[4];
#pragma unroll
  for (int r = 0; r < 4; ++r) li[r] = 1.0f / __shfl(l_run, lr * 4 + r);
  uint16_t* orow = ctxlatb + (size_t)(b * 1024 + s0 + wave * 16) * 2048 + h * 128;
#pragma unroll
  for (int nt = 0; nt < 8; ++nt)
#pragma unroll
    for (int r = 0; r < 4; ++r)
      orow[(size_t)(lr * 4 + r) * 2048 + nt * 16 + lc] = f2b(o[nt][r] * li[r]);
}

extern "C" void kernel_launch(void* const* d_in, const int* in_sizes, int n_in,
                              void* d_out, int out_size, void* d_ws, size_t ws_size,
                              hipStream_t stream) {
  const float* hidden_q = (const float*)d_in[0];
  const float* kv_c = (const float*)d_in[1];
  const float* Wq = (const float*)d_in[2];
  const float* w_kc_q = (const float*)d_in[3];
  const float* W_qr = (const float*)d_in[4];
  const float* W_kr = (const float*)d_in[5];
  const float* w_kc_kv = (const float*)d_in[6];
  const float* Wo = (const float*)d_in[7];
  float* out = (float*)d_out;

  const size_t MB = 1024 * 1024;
  uint8_t* base = (uint8_t*)d_ws;
  // --- live through flash ---
  uint16_t* Wob = (uint16_t*)(base + 0 * MB);       // 8 MiB
  uint16_t* qrb = (uint16_t*)(base + 8 * MB);       // 4 MiB [2048][1024] (q pre-scaled log2e)
  uint16_t* krb = (uint16_t*)(base + 12 * MB);      // 4 MiB [2048][1024]
  uint16_t* VhT = (uint16_t*)(base + 16 * MB);      // 8 MiB [b*2048+h*128+kk][1024]
  uint16_t* ctxlatb = (uint16_t*)(base + 24 * MB);  // 8 MiB [b*1024+s][2048]
  // --- prep stage (dead by flash time) ---
  float* cosK = (float*)(base + 32 * MB);
  float* sinK = (float*)(base + 32 * MB + 262144);
  float* cosQ = (float*)(base + 32 * MB + 524288);
  float* sinQ = (float*)(base + 32 * MB + 786432);
  uint16_t* hqb = (uint16_t*)(base + 33 * MB);      // 8 MiB
  uint16_t* kvb = (uint16_t*)(base + 41 * MB);      // 2 MiB
  uint16_t* wkvb = (uint16_t*)(base + 43 * MB);     // 2 MiB
  uint16_t* WqT = (uint16_t*)(base + 45 * MB);      // 8 MiB
  uint16_t* WqrT = (uint16_t*)(base + 53 * MB);     // 3 MiB
  uint16_t* wkcqb = (uint16_t*)(base + 56 * MB);    // 6 MiB
  float* tmp1 = (float*)(base + 62 * MB);           // 2 MiB f32 fold1 partials [16][4][8192]
  uint16_t* tmpT = (uint16_t*)(base + 64 * MB);     // 256 KiB
  uint16_t* WkrT = (uint16_t*)(base + 64 * MB + 262144);  // 1 MiB

  convert5_kernel<<<dim3(6656), dim3(256), 0, stream>>>(hidden_q, hqb, kv_c, kvb, w_kc_kv, wkvb,
                                                        Wo, Wob, w_kc_q, wkcqb);
  rope_tables_kernel<<<dim3(1024), dim3(64), 0, stream>>>(cosK, sinK, cosQ, sinQ);
  // W_qr [h][1536][64] -> WqrT [h][64][1536]
  transpose_conv_kernel<<<dim3(48, 2, 16), dim3(256), 0, stream>>>((const float*)W_qr, WqrT, 1536,
                                                                   64, 98304, 98304);
  // Wq [2048][2048] -> WqT [2048][2048]
  transpose_conv_kernel<<<dim3(64, 64, 1), dim3(256), 0, stream>>>(Wq, WqT, 2048, 2048, 0, 0);
  // W_kr [h][512][64] -> WkrT [h][64][512]
  transpose_conv_kernel<<<dim3(16, 2, 16), dim3(256), 0, stream>>>((const float*)W_kr, WkrT, 512,
                                                                   64, 32768, 32768);
  // fold1 split-K x4: tmp1[h*4+zk] = partial sum over q in [zk*384,(zk+1)*384)
  gemm_mfma_kernel<64, 0, 4><<<dim3(1, 1, 64), dim3(256), 0, stream>>>(
      WqrT, wkcqb, tmp1, 384, 1536, 1536, 128, 98304, 196608, 8192, nullptr, nullptr);
  reduce1_kernel<<<dim3(512), dim3(256), 0, stream>>>(tmp1, tmpT);
  // fold2: WfoldT[h*64+r][d] = sum_k tmpT[h][r][k] * WqT[d][h*128+k]  (M=64,N=2048,K=128)
  // WfoldT overlays wkcqb (dead after fold1+reduce)
  uint16_t* WfoldT = wkcqb;
  gemm_mfma_kernel<64, 1><<<dim3(1, 16, 16), dim3(256), 0, stream>>>(
      tmpT, WqT, WfoldT, 128, 128, 2048, 2048, 8192, 128, 131072, nullptr, nullptr);
  // qr = rope_q(hqb @ WfoldT^T) [2048][1024], fused rope with log2e-scaled tables
  gemm_mfma_kernel<64, 3><<<dim3(32, 8), dim3(256), 0, stream>>>(hqb, WfoldT, qrb, 2048, 2048,
                                                                 2048, 1024, 0, 0, 0, cosQ, sinQ);
  // kr = rope_k(kvb @ WkrT^T) [2048][1024]
  gemm_mfma_kernel<64, 3><<<dim3(32, 8), dim3(256), 0, stream>>>(kvb, WkrT, krb, 512, 512, 512,
                                                                 1024, 0, 0, 0, cosK, sinK);
  // VhT[b*2048+h*128+kk][l] via EPI=2
  gemm_mfma_kernel<64, 2><<<dim3(32, 16), dim3(256), 0, stream>>>(kvb, wkvb, VhT, 512, 512, 512, 0,
                                                                  0, 0, 0, nullptr, nullptr);
  // fused flash attention -> ctxlatb
  flash3_kernel<<<dim3(32, 16), dim3(256), 0, stream>>>(qrb, krb, VhT, ctxlatb);
  // out = ctxlatb @ Wob^T  [2048][2048] f32
  gemm_mfma_kernel<64, 0><<<dim3(32, 16), dim3(256), 0, stream>>>(ctxlatb, Wob, out, 2048, 2048,
                                                                  2048, 2048, 0, 0, 0, nullptr,
                                                                  nullptr);
}

// Round 9
// 151.000 us; speedup vs baseline: 1.1849x; 1.0140x over previous
//
#include <hip/hip_runtime.h>
#include <math.h>
#include <stdint.h>

// Sizes (fixed): B=2, S=L=1024, h=16, k=128, d_c=512, d_cq=1536, r=64, dim_q=2048

typedef __attribute__((ext_vector_type(8))) short short8;
typedef __attribute__((ext_vector_type(4))) float f32x4;

#define GLOAD16(gsrc, ldst)                                                            \
  __builtin_amdgcn_global_load_lds((const __attribute__((address_space(1))) void*)(gsrc), \
                                   (__attribute__((address_space(3))) void*)(ldst), 16, 0, 0)

__device__ inline uint16_t f2b(float x) {  // round-to-nearest-even f32 -> bf16
  uint32_t u = __builtin_bit_cast(uint32_t, x);
  u += 0x7fff + ((u >> 16) & 1);
  return (uint16_t)(u >> 16);
}
__device__ inline float b2f(uint16_t b) {
  uint32_t u = ((uint32_t)b) << 16;
  return __builtin_bit_cast(float, u);
}
__device__ inline uint32_t cvtpk_bf16(float lo, float hi) {  // packs 2 f32 -> 2 bf16 (RNE)
  uint32_t d;
  asm("v_cvt_pk_bf16_f32 %0, %1, %2" : "=v"(d) : "v"(lo), "v"(hi));
  return d;
}

// ---------------- fused f32 -> bf16 convert for 5 buffers (8 el/thread) ----------------
// block counts: hq 2048 | kv 512 | wkv 512 | Wo 2048 | wkcq 1536  (total 6656)
__global__ __launch_bounds__(256) void convert5_kernel(
    const float* __restrict__ s0, uint16_t* __restrict__ t0, const float* __restrict__ s1,
    uint16_t* __restrict__ t1, const float* __restrict__ s2, uint16_t* __restrict__ t2,
    const float* __restrict__ s3, uint16_t* __restrict__ t3, const float* __restrict__ s4,
    uint16_t* __restrict__ t4) {
  int bid = blockIdx.x;
  const float* s;
  uint16_t* t;
  int off;
  if (bid < 2048) { s = s0; t = t0; off = bid; }
  else if (bid < 2560) { s = s1; t = t1; off = bid - 2048; }
  else if (bid < 3072) { s = s2; t = t2; off = bid - 2560; }
  else if (bid < 5120) { s = s3; t = t3; off = bid - 3072; }
  else { s = s4; t = t4; off = bid - 5120; }
  int i = off * 256 + threadIdx.x;
  const float4* s4v = (const float4*)s;
  float4 a = s4v[i * 2], b = s4v[i * 2 + 1];
  union {
    uint16_t u[8];
    uint4 v;
  } o;
  o.u[0] = f2b(a.x); o.u[1] = f2b(a.y); o.u[2] = f2b(a.z); o.u[3] = f2b(a.w);
  o.u[4] = f2b(b.x); o.u[5] = f2b(b.y); o.u[6] = f2b(b.z); o.u[7] = f2b(b.w);
  ((uint4*)t)[i] = o.v;
}

// ---------------- tiled transpose + convert: src f32 [R][C] -> dst bf16 [C][R] ----------------
__global__ __launch_bounds__(256) void transpose_conv_kernel(const float* __restrict__ src,
                                                             uint16_t* __restrict__ dst,
                                                             int R, int C, int sOff, int dOff) {
  __shared__ float t[32][33];
  src += (size_t)blockIdx.z * sOff;
  dst += (size_t)blockIdx.z * dOff;
  int r0 = blockIdx.x * 32, c0 = blockIdx.y * 32;
  int tr = threadIdx.x >> 5, tc = threadIdx.x & 31;
#pragma unroll
  for (int i = 0; i < 4; ++i) t[tr + i * 8][tc] = src[(size_t)(r0 + tr + i * 8) * C + c0 + tc];
  __syncthreads();
#pragma unroll
  for (int i = 0; i < 4; ++i)
    dst[(size_t)(c0 + tr + i * 8) * R + r0 + tc] = f2b(t[tc][tr + i * 8]);
}

// ---------------- rope tables: K-tables plain, Q-tables pre-scaled by log2(e) ----------------
__global__ __launch_bounds__(64) void rope_tables_kernel(float* __restrict__ cosK,
                                                         float* __restrict__ sinK,
                                                         float* __restrict__ cosQ,
                                                         float* __restrict__ sinQ) {
  const float LOG2E = 1.44269504088896341f;
  int s = blockIdx.x;
  int j = threadIdx.x;
  int i = j & 31;
  float inv = powf(10000.0f, -(float)(2 * i) / 64.0f);
  float ang = (float)s * inv;
  float c = cosf(ang), sn = sinf(ang);
  cosK[s * 64 + j] = c;
  sinK[s * 64 + j] = sn;
  cosQ[s * 64 + j] = c * LOG2E;
  sinQ[s * 64 + j] = sn * LOG2E;
}

// ---------------- MFMA GEMM: C[.., M, N] = A[z][M,K]bf16 @ Bt[z][N,K]bf16^T ----------------
// Tile BM x 128, BK=64, 256 thr (4 waves 2x2), XOR slot swizzle, global_load_lds staging,
// DOUBLE-BUFFERED: next K-tile's loads issued before current tile's compute; 1 barrier/iter.
// EPI 0: f32 row-major; 1: bf16 row-major; 2: bf16 VhT layout; 3: bf16 + fused rope.
// SPLITK>1: z = zh*SPLITK+zk; A/Bt K-offset zk*K; C indexed linearly by z (cZ).
template <int BM, int EPI, int SPLITK = 1>
__global__ __launch_bounds__(256) void gemm_mfma_kernel(const uint16_t* __restrict__ A,
                                                        const uint16_t* __restrict__ Bt,
                                                        void* __restrict__ Cv, int K, int lda,
                                                        int ldb, int ldc, int aZ, int bZ, int cZ,
                                                        const float* __restrict__ rc,
                                                        const float* __restrict__ rs) {
  constexpr int MT = BM / 32;  // m-fragments per wave (2 or 4)
  __shared__ __align__(16) uint16_t As[2][BM * 64];
  __shared__ __align__(16) uint16_t Bs[2][128 * 64];
  int z = blockIdx.z;
  if (SPLITK > 1) {
    int zh = z / SPLITK, zk = z % SPLITK;
    A += (size_t)zh * aZ + (size_t)zk * K;
    Bt += (size_t)zh * bZ + (size_t)zk * K;
  } else {
    A += (size_t)z * aZ;
    Bt += (size_t)z * bZ;
  }
  int m0 = blockIdx.x * BM, n0 = blockIdx.y * 128;
  int tid = threadIdx.x;
  int wave = tid >> 6, lane = tid & 63;
  int wm = wave >> 1, wn = wave & 1;
  int rS = lane >> 3, sl = lane & 7;
  int lr = lane >> 4, lc = lane & 15;

  auto stage = [&](int k0, int buf) {
#pragma unroll
    for (int i = 0; i < MT; ++i) {
      int idx = wave * MT + i;
      int row = idx * 8 + rS;
      GLOAD16(A + (size_t)(m0 + row) * lda + k0 + ((sl ^ (row & 7)) << 3),
              (uint8_t*)As[buf] + idx * 1024);
    }
#pragma unroll
    for (int i = 0; i < 4; ++i) {
      int idx = wave * 4 + i;
      int row = idx * 8 + rS;
      GLOAD16(Bt + (size_t)(n0 + row) * ldb + k0 + ((sl ^ (row & 7)) << 3),
              (uint8_t*)Bs[buf] + idx * 1024);
    }
  };

  f32x4 acc[MT][4] = {};
  stage(0, 0);
  int cur = 0;
  for (int k0 = 0; k0 < K; k0 += 64) {
    __syncthreads();  // drains vmcnt -> buf[cur] ready; prev iter's LDS reads done
    if (k0 + 64 < K) stage(k0 + 64, cur ^ 1);  // prefetch next tile (latency hidden)
    short8 af[MT][2], bf[4][2];
#pragma unroll
    for (int t = 0; t < MT; ++t)
#pragma unroll
      for (int ks = 0; ks < 2; ++ks) {
        int slot = ks * 4 + lr;
        int ra = wm * (BM / 2) + t * 16 + lc;
        af[t][ks] =
            *(const short8*)((const uint8_t*)As[cur] + ra * 128 + ((slot ^ (ra & 7)) << 4));
      }
#pragma unroll
    for (int t = 0; t < 4; ++t)
#pragma unroll
      for (int ks = 0; ks < 2; ++ks) {
        int slot = ks * 4 + lr;
        int rb = wn * 64 + t * 16 + lc;
        bf[t][ks] =
            *(const short8*)((const uint8_t*)Bs[cur] + rb * 128 + ((slot ^ (rb & 7)) << 4));
      }
    __builtin_amdgcn_s_setprio(1);
#pragma unroll
    for (int mt = 0; mt < MT; ++mt)
#pragma unroll
      for (int nt = 0; nt < 4; ++nt) {
        acc[mt][nt] =
            __builtin_amdgcn_mfma_f32_16x16x32_bf16(af[mt][0], bf[nt][0], acc[mt][nt], 0, 0, 0);
        acc[mt][nt] =
            __builtin_amdgcn_mfma_f32_16x16x32_bf16(af[mt][1], bf[nt][1], acc[mt][nt], 0, 0, 0);
      }
    __builtin_amdgcn_s_setprio(0);
    cur ^= 1;
  }
  if (EPI == 3) {
#pragma unroll
    for (int mt = 0; mt < MT; ++mt)
#pragma unroll
      for (int nt = 0; nt < 4; ++nt)
#pragma unroll
        for (int r = 0; r < 4; ++r) {
          int m = m0 + wm * (BM / 2) + mt * 16 + lr * 4 + r;
          int n = n0 + wn * 64 + nt * 16 + lc;
          int pos = m & 1023, j = n & 63;
          float x = acc[mt][nt][r];
          float prt = acc[mt][nt ^ 2][r];
          float rot = (nt & 2) ? prt : -prt;
          float v = fmaf(x, rc[pos * 64 + j], rot * rs[pos * 64 + j]);
          ((uint16_t*)Cv)[(size_t)m * ldc + n] = f2b(v);
        }
  } else {
#pragma unroll
    for (int mt = 0; mt < MT; ++mt)
#pragma unroll
      for (int nt = 0; nt < 4; ++nt)
#pragma unroll
        for (int r = 0; r < 4; ++r) {
          int m = m0 + wm * (BM / 2) + mt * 16 + lr * 4 + r;
          int n = n0 + wn * 64 + nt * 16 + lc;
          float v = acc[mt][nt][r];
          if (EPI == 0)
            ((float*)Cv)[(size_t)z * cZ + (size_t)m * ldc + n] = v;
          else if (EPI == 1)
            ((uint16_t*)Cv)[(size_t)z * cZ + (size_t)m * ldc + n] = f2b(v);
          else
            ((uint16_t*)Cv)[((size_t)((m >> 10) * 2048 + n)) * 1024 + (m & 1023)] = f2b(v);
        }
  }
}

// ---------------- reduce fold1 split-K partials f32 -> bf16 ----------------
// tp: [16 heads][4 splits][8192], out: [16][8192] bf16
__global__ __launch_bounds__(256) void reduce1_kernel(const float* __restrict__ tp,
                                                      uint16_t* __restrict__ tmpT) {
  int gid = blockIdx.x * 256 + threadIdx.x;  // 131072
  int zh = gid >> 13, e = gid & 8191;
  const float* b = tp + (size_t)zh * 32768 + e;
  tmpT[gid] = f2b(b[0] + b[8192] + b[16384] + b[24576]);
}

// ---------------- MFMA flash attention, swapped QK^T, IN-BLOCK KV-SPLIT ----------------
// grid (bh=32, stile=16), 512 thr = 8 waves: group ig = wave>>2 handles l in [ig*512, ig*512+512);
// wave w = wave&3 owns q-rows w*16..+15 (same rows in both groups). Single-buffered per-group
// K/V staging. Partials merged in LDS at epilogue. exp2 domain (q pre-scaled by log2e).
// Out: ctxlatb bf16 [b*1024+s][2048]
__global__ __launch_bounds__(512, 4) void flash3_kernel(const uint16_t* __restrict__ qrb,
                                                        const uint16_t* __restrict__ krb,
                                                        const uint16_t* __restrict__ VhT,
                                                        uint16_t* __restrict__ ctxlatb) {
  // LDS map: Ks 2x8KB @0 | Vs 2x16KB @16384 | Ps 8x2304B @49152 | epilogue: O1 f32[64][130] @0,
  // ml float2[2][4][16] @49152 (Ps region, dead by then)
  __shared__ __align__(16) uint8_t lds[67584];
  int bh = blockIdx.x;
  int b = bh >> 4, h = bh & 15;
  int s0 = blockIdx.y * 64;
  int tid = threadIdx.x, wave = tid >> 6, lane = tid & 63;
  int ig = wave >> 2, w = wave & 3;
  int lr = lane >> 4, lc = lane & 15;
  int rS = lane >> 3, sl = lane & 7;

  uint8_t* Ks = lds + ig * 8192;
  uint8_t* Vs = lds + 16384 + ig * 16384;
  uint8_t* Ps = lds + 49152 + wave * 2304;

  const uint16_t* qrow = qrb + (size_t)(b * 1024 + s0 + w * 16 + lc) * 1024 + h * 64;
  short8 qa[2];
  qa[0] = *(const short8*)(qrow + lr * 8);
  qa[1] = *(const short8*)(qrow + 32 + lr * 8);

  // per-lane softmax state for q-row lc (replicated across lr groups)
  float m_run = -1e30f, l_run = 0.f;
  f32x4 o[8] = {};

  uint8_t* psW = Ps + lc * 144 + lr * 8;
  const uint8_t* psR = Ps + lc * 144 + lr * 16;

  const uint16_t* krbase = krb + (size_t)(b * 1024) * 1024 + h * 64;
  const uint16_t* vtbase = VhT + (size_t)(b * 2048 + h * 128) * 1024;

  auto stageKV = [&](int l0) {
#pragma unroll
    for (int i = 0; i < 2; ++i) {  // K tile: 8KB (8 rows per gload per wave)
      int idx = w * 2 + i;
      int row = idx * 8 + rS;
      GLOAD16(krbase + (size_t)(l0 + row) * 1024 + ((sl ^ (row & 7)) << 3), Ks + idx * 1024);
    }
#pragma unroll
    for (int i = 0; i < 4; ++i) {  // V^T tile: 16KB
      int idx = w * 4 + i;
      int row = idx * 8 + rS;
      GLOAD16(vtbase + (size_t)row * 1024 + l0 + ((sl ^ (row & 7)) << 3), Vs + idx * 1024);
    }
  };

  for (int t = 0; t < 8; ++t) {
    int l0 = ig * 512 + t * 64;
    __syncthreads();  // previous compute's LDS reads complete (both groups)
    stageKV(l0);
    __syncthreads();  // vmcnt drained -> tiles visible

    // QK^T swapped: sc[nt] rows = k (nt*16 + lr*4+r), col = q-row (lc)
    f32x4 sc[4];
    __builtin_amdgcn_s_setprio(1);
#pragma unroll
    for (int nt = 0; nt < 4; ++nt) {
      int rowk = nt * 16 + lc;
      short8 kb0 = *(const short8*)(Ks + rowk * 128 + ((lr ^ (rowk & 7)) << 4));
      short8 kb1 = *(const short8*)(Ks + rowk * 128 + (((4 + lr) ^ (rowk & 7)) << 4));
      f32x4 z = {};
      z = __builtin_amdgcn_mfma_f32_16x16x32_bf16(kb0, qa[0], z, 0, 0, 0);
      sc[nt] = __builtin_amdgcn_mfma_f32_16x16x32_bf16(kb1, qa[1], z, 0, 0, 0);
    }
    __builtin_amdgcn_s_setprio(0);

    // lane-local max over 16 k-values, then 2-shuffle reduce across lr-group
    float mx = fmaxf(fmaxf(fmaxf(sc[0][0], sc[0][1]), fmaxf(sc[0][2], sc[0][3])),
                     fmaxf(fmaxf(sc[1][0], sc[1][1]), fmaxf(sc[1][2], sc[1][3])));
    float mx2 = fmaxf(fmaxf(fmaxf(sc[2][0], sc[2][1]), fmaxf(sc[2][2], sc[2][3])),
                      fmaxf(fmaxf(sc[3][0], sc[3][1]), fmaxf(sc[3][2], sc[3][3])));
    mx = fmaxf(mx, mx2);
    mx = fmaxf(mx, __shfl_xor(mx, 16));
    mx = fmaxf(mx, __shfl_xor(mx, 32));

    // defer-max: skip rescale when max grew <= 8 (log2 domain -> P <= 256)
    bool grow = mx > m_run + 8.0f;
    bool upd = (__ballot(grow) != 0ULL);  // wave-uniform
    float scale;
    if (upd) {
      float mn = fmaxf(m_run, mx);
      scale = exp2f(m_run - mn);
      m_run = mn;
    }

    // P = exp2(sc - m), packed bf16 stores at base + immediate (k = nt*16+lr*4+rp*2)
    float ps = 0.f;
#pragma unroll
    for (int nt = 0; nt < 4; ++nt) {
#pragma unroll
      for (int rp = 0; rp < 2; ++rp) {
        float p0 = exp2f(sc[nt][rp * 2] - m_run);
        float p1 = exp2f(sc[nt][rp * 2 + 1] - m_run);
        ps += p0 + p1;
        *(uint32_t*)(psW + nt * 32 + rp * 4) = cvtpk_bf16(p0, p1);
      }
    }
    ps += __shfl_xor(ps, 16);
    ps += __shfl_xor(ps, 32);

    if (upd) {
      l_run = l_run * scale + ps;
      float sc0 = __shfl(scale, lr * 4 + 0);
      float sc1 = __shfl(scale, lr * 4 + 1);
      float sc2 = __shfl(scale, lr * 4 + 2);
      float sc3 = __shfl(scale, lr * 4 + 3);
#pragma unroll
      for (int nt = 0; nt < 8; ++nt) {
        o[nt][0] *= sc0;
        o[nt][1] *= sc1;
        o[nt][2] *= sc2;
        o[nt][3] *= sc3;
      }
    } else {
      l_run += ps;
    }

    // P as A-fragment (row = q = lc, k elems ks*32 + lr*8): 2 reads at base + immediate
    short8 pa[2];
    pa[0] = *(const short8*)(psR);
    pa[1] = *(const short8*)(psR + 64);
    // PV: o[nt] rows = q (lr*4+r), col = kk (nt*16+lc)
    __builtin_amdgcn_s_setprio(1);
#pragma unroll
    for (int nt = 0; nt < 8; ++nt) {
      int rowv = nt * 16 + lc;
      short8 vb0 = *(const short8*)(Vs + rowv * 128 + ((lr ^ (rowv & 7)) << 4));
      short8 vb1 = *(const short8*)(Vs + rowv * 128 + (((4 + lr) ^ (rowv & 7)) << 4));
      o[nt] = __builtin_amdgcn_mfma_f32_16x16x32_bf16(pa[0], vb0, o[nt], 0, 0, 0);
      o[nt] = __builtin_amdgcn_mfma_f32_16x16x32_bf16(pa[1], vb1, o[nt], 0, 0, 0);
    }
    __builtin_amdgcn_s_setprio(0);
  }

  // ---- epilogue: merge the two kv-halves in LDS ----
  __syncthreads();  // all groups done with Ks/Vs/Ps
  float2* mlx = (float2*)(lds + 49152);
  if (lr == 0) mlx[(ig * 4 + w) * 16 + lc] = make_float2(m_run, l_run);
  __syncthreads();
  float2 e0 = mlx[(0 * 4 + w) * 16 + lc];
  float2 e1 = mlx[(1 * 4 + w) * 16 + lc];
  float M = fmaxf(e0.x, e1.x);
  float a0 = exp2f(e0.x - M), a1 = exp2f(e1.x - M);
  float dinv = 1.0f / (e0.y * a0 + e1.y * a1);
  float myA = ig ? a1 : a0;
  float ar[4], dr[4];
#pragma unroll
  for (int r = 0; r < 4; ++r) {
    ar[r] = __shfl(myA, lr * 4 + r);
    dr[r] = __shfl(dinv, lr * 4 + r);
  }
  float* O1 = (float*)lds;  // [64 q][stride 130] f32 = 33280 B
  int qb = w * 16 + lr * 4;
  if (ig == 1) {
#pragma unroll
    for (int nt = 0; nt < 8; ++nt)
#pragma unroll
      for (int r = 0; r < 4; ++r) O1[(qb + r) * 130 + nt * 16 + lc] = o[nt][r] * ar[r];
  }
  __syncthreads();
  if (ig == 0) {
    uint16_t* orow = ctxlatb + (size_t)(b * 1024 + s0 + w * 16) * 2048 + h * 128;
#pragma unroll
    for (int nt = 0; nt < 8; ++nt)
#pragma unroll
      for (int r = 0; r < 4; ++r) {
        float v = (o[nt][r] * ar[r] + O1[(qb + r) * 130 + nt * 16 + lc]) * dr[r];
        orow[(size_t)(lr * 4 + r) * 2048 + nt * 16 + lc] = f2b(v);
      }
  }
}

extern "C" void kernel_launch(void* const* d_in, const int* in_sizes, int n_in,
                              void* d_out, int out_size, void* d_ws, size_t ws_size,
                              hipStream_t stream) {
  const float* hidden_q = (const float*)d_in[0];
  const float* kv_c = (const float*)d_in[1];
  const float* Wq = (const float*)d_in[2];
  const float* w_kc_q = (const float*)d_in[3];
  const float* W_qr = (const float*)d_in[4];
  const float* W_kr = (const float*)d_in[5];
  const float* w_kc_kv = (const float*)d_in[6];
  const float* Wo = (const float*)d_in[7];
  float* out = (float*)d_out;

  const size_t MB = 1024 * 1024;
  uint8_t* base = (uint8_t*)d_ws;
  // --- live through flash ---
  uint16_t* Wob = (uint16_t*)(base + 0 * MB);       // 8 MiB
  uint16_t* qrb = (uint16_t*)(base + 8 * MB);       // 4 MiB [2048][1024] (q pre-scaled log2e)
  uint16_t* krb = (uint16_t*)(base + 12 * MB);      // 4 MiB [2048][1024]
  uint16_t* VhT = (uint16_t*)(base + 16 * MB);      // 8 MiB [b*2048+h*128+kk][1024]
  uint16_t* ctxlatb = (uint16_t*)(base + 24 * MB);  // 8 MiB [b*1024+s][2048]
  // --- prep stage (dead by flash time) ---
  float* cosK = (float*)(base + 32 * MB);
  float* sinK = (float*)(base + 32 * MB + 262144);
  float* cosQ = (float*)(base + 32 * MB + 524288);
  float* sinQ = (float*)(base + 32 * MB + 786432);
  uint16_t* hqb = (uint16_t*)(base + 33 * MB);      // 8 MiB
  uint16_t* kvb = (uint16_t*)(base + 41 * MB);      // 2 MiB
  uint16_t* wkvb = (uint16_t*)(base + 43 * MB);     // 2 MiB
  uint16_t* WqT = (uint16_t*)(base + 45 * MB);      // 8 MiB
  uint16_t* WqrT = (uint16_t*)(base + 53 * MB);     // 3 MiB
  uint16_t* wkcqb = (uint16_t*)(base + 56 * MB);    // 6 MiB
  float* tmp1 = (float*)(base + 62 * MB);           // 2 MiB f32 fold1 partials [16][4][8192]
  uint16_t* tmpT = (uint16_t*)(base + 64 * MB);     // 256 KiB
  uint16_t* WkrT = (uint16_t*)(base + 64 * MB + 262144);  // 1 MiB

  convert5_kernel<<<dim3(6656), dim3(256), 0, stream>>>(hidden_q, hqb, kv_c, kvb, w_kc_kv, wkvb,
                                                        Wo, Wob, w_kc_q, wkcqb);
  rope_tables_kernel<<<dim3(1024), dim3(64), 0, stream>>>(cosK, sinK, cosQ, sinQ);
  // W_qr [h][1536][64] -> WqrT [h][64][1536]
  transpose_conv_kernel<<<dim3(48, 2, 16), dim3(256), 0, stream>>>((const float*)W_qr, WqrT, 1536,
                                                                   64, 98304, 98304);
  // Wq [2048][2048] -> WqT [2048][2048]
  transpose_conv_kernel<<<dim3(64, 64, 1), dim3(256), 0, stream>>>(Wq, WqT, 2048, 2048, 0, 0);
  // W_kr [h][512][64] -> WkrT [h][64][512]
  transpose_conv_kernel<<<dim3(16, 2, 16), dim3(256), 0, stream>>>((const float*)W_kr, WkrT, 512,
                                                                   64, 32768, 32768);
  // fold1 split-K x4: tmp1[h*4+zk] = partial sum over q in [zk*384,(zk+1)*384)
  gemm_mfma_kernel<64, 0, 4><<<dim3(1, 1, 64), dim3(256), 0, stream>>>(
      WqrT, wkcqb, tmp1, 384, 1536, 1536, 128, 98304, 196608, 8192, nullptr, nullptr);
  reduce1_kernel<<<dim3(512), dim3(256), 0, stream>>>(tmp1, tmpT);
  // fold2: WfoldT[h*64+r][d] = sum_k tmpT[h][r][k] * WqT[d][h*128+k]  (M=64,N=2048,K=128)
  // WfoldT overlays wkcqb (dead after fold1+reduce)
  uint16_t* WfoldT = wkcqb;
  gemm_mfma_kernel<64, 1><<<dim3(1, 16, 16), dim3(256), 0, stream>>>(
      tmpT, WqT, WfoldT, 128, 128, 2048, 2048, 8192, 128, 131072, nullptr, nullptr);
  // qr = rope_q(hqb @ WfoldT^T) [2048][1024], fused rope with log2e-scaled tables
  gemm_mfma_kernel<64, 3><<<dim3(32, 8), dim3(256), 0, stream>>>(hqb, WfoldT, qrb, 2048, 2048,
                                                                 2048, 1024, 0, 0, 0, cosQ, sinQ);
  // kr = rope_k(kvb @ WkrT^T) [2048][1024]
  gemm_mfma_kernel<64, 3><<<dim3(32, 8), dim3(256), 0, stream>>>(kvb, WkrT, krb, 512, 512, 512,
                                                                 1024, 0, 0, 0, cosK, sinK);
  // VhT[b*2048+h*128+kk][l] via EPI=2
  gemm_mfma_kernel<64, 2><<<dim3(32, 16), dim3(256), 0, stream>>>(kvb, wkvb, VhT, 512, 512, 512, 0,
                                                                  0, 0, 0, nullptr, nullptr);
  // fused flash attention (in-block kv-split, 8 waves) -> ctxlatb
  flash3_kernel<<<dim3(32, 16), dim3(512), 0, stream>>>(qrb, krb, VhT, ctxlatb);
  // out = ctxlatb @ Wob^T  [2048][2048] f32
  gemm_mfma_kernel<64, 0><<<dim3(32, 16), dim3(256), 0, stream>>>(ctxlatb, Wob, out, 2048, 2048,
                                                                  2048, 2048, 0, 0, 0, nullptr,
                                                                  nullptr);
}